// Round 1
// baseline (1165.505 us; speedup 1.0000x reference)
//
#include <hip/hip_runtime.h>
#include <math.h>

static constexpr int Tt = 32;
static constexpr int Nn = 1024;
static constexpr int KN = 16;   // K + self

// ---------------------------------------------------------------------------
// 1. Recover source indices: srcs[t,k,tgt] = k-th smallest src with edge=1,
//    srcs[t,15,tgt] = tgt (self loop). Order-invariant for GAT anyway.
// ---------------------------------------------------------------------------
__global__ __launch_bounds__(256) void k_srcs(const int* __restrict__ edge,
                                              int* __restrict__ srcs)
{
    int tn = blockIdx.x * blockDim.x + threadIdx.x;   // 0..T*N-1
    int t = tn >> 10, tgt = tn & (Nn - 1);
    const int* e = edge + (size_t)t * Nn * Nn + tgt;
    int cnt = 0;
    for (int s = 0; s < Nn; ++s) {
        if (e[(size_t)s * Nn] != 0) {
            if (cnt < KN - 1) srcs[(t * KN + cnt) * Nn + tgt] = s;
            ++cnt;
        }
    }
    srcs[(t * KN + (KN - 1)) * Nn + tgt] = tgt;
}

// ---------------------------------------------------------------------------
// 2. Y[row,col] = b[col] + sum_i X[row,i] * W[i,col]
//    blockDim = (fo, 256/fo)
// ---------------------------------------------------------------------------
__global__ void k_lin(const float* __restrict__ X, const float* __restrict__ W,
                      const float* __restrict__ b, float* __restrict__ Y,
                      int rows, int fi, int fo)
{
    int col = threadIdx.x;
    int row = blockIdx.x * blockDim.y + threadIdx.y;
    if (row >= rows) return;
    float acc = b[col];
    const float* xr = X + (size_t)row * fi;
    for (int i = 0; i < fi; ++i)
        acc = fmaf(xr[i], W[i * fo + col], acc);
    Y[(size_t)row * fo + col] = acc;
}

// ---------------------------------------------------------------------------
// 3. GATv2 attention + aggregate + mean-heads + bias + ELU.
//    One wave per (t, target). H=2 heads fixed. C = per-head channels.
//    gl/gr: [rows, 2*C]; srcs (pre-offset): [*,16,N]; out: [rows, C]
// ---------------------------------------------------------------------------
template <int C>
__global__ __launch_bounds__(256) void k_gat(
    const float* __restrict__ gl, const float* __restrict__ gr,
    const int* __restrict__ srcs, const float* __restrict__ att,
    const float* __restrict__ bias, float* __restrict__ out, int rows)
{
    constexpr int HC = 2 * C;
    __shared__ float lds[4][KN][HC];
    const int lane = threadIdx.x & 63;
    const int w = threadIdx.x >> 6;
    const int wave = blockIdx.x * 4 + w;
    if (wave >= rows) return;            // grid sized so this never fires
    const int t = wave >> 10;
    const int n = wave & (Nn - 1);

    float lo0[KN], lo1[KN];

    if (C == 64) {
        const float grl0 = gr[(size_t)wave * HC + lane];
        const float grl1 = gr[(size_t)wave * HC + 64 + lane];
        const float a0 = att[lane], a1 = att[64 + lane];
#pragma unroll
        for (int k = 0; k < KN; ++k) {
            int s = srcs[(t * KN + k) * Nn + n];
            const float* gsr = gl + ((size_t)t * Nn + s) * HC;
            float g0 = gsr[lane], g1 = gsr[64 + lane];
            lds[w][k][lane] = g0;
            lds[w][k][64 + lane] = g1;
            float e0 = g0 + grl0; e0 = e0 > 0.0f ? e0 : 0.2f * e0;
            float e1 = g1 + grl1; e1 = e1 > 0.0f ? e1 : 0.2f * e1;
            float p0 = e0 * a0, p1 = e1 * a1;
#pragma unroll
            for (int m = 1; m < 64; m <<= 1) {
                p0 += __shfl_xor(p0, m);
                p1 += __shfl_xor(p1, m);
            }
            lo0[k] = p0; lo1[k] = p1;
        }
    } else {
        const float grl = gr[(size_t)wave * HC + lane];
        const float a = att[lane];
#pragma unroll
        for (int k = 0; k < KN; ++k) {
            int s = srcs[(t * KN + k) * Nn + n];
            const float* gsr = gl + ((size_t)t * Nn + s) * HC;
            float g = gsr[lane];
            lds[w][k][lane] = g;
            float e = g + grl; e = e > 0.0f ? e : 0.2f * e;
            float p = e * a;
#pragma unroll
            for (int m = 1; m < 32; m <<= 1) p += __shfl_xor(p, m);
            float o = __shfl_xor(p, 32);
            lo0[k] = (lane < 32) ? p : o;
            lo1[k] = (lane < 32) ? o : p;
        }
    }

    __syncthreads();

    // softmax over the 16 neighbors, both heads (all lanes have full logits)
    float m0 = lo0[0], m1 = lo1[0];
#pragma unroll
    for (int k = 1; k < KN; ++k) { m0 = fmaxf(m0, lo0[k]); m1 = fmaxf(m1, lo1[k]); }
    float s0 = 0.0f, s1 = 0.0f;
#pragma unroll
    for (int k = 0; k < KN; ++k) {
        lo0[k] = expf(lo0[k] - m0); s0 += lo0[k];
        lo1[k] = expf(lo1[k] - m1); s1 += lo1[k];
    }
    const float inv0 = 1.0f / s0, inv1 = 1.0f / s1;

    if (C == 64) {
        float acc0 = 0.0f, acc1 = 0.0f;
#pragma unroll
        for (int k = 0; k < KN; ++k) {
            acc0 = fmaf(lo0[k] * inv0, lds[w][k][lane], acc0);
            acc1 = fmaf(lo1[k] * inv1, lds[w][k][64 + lane], acc1);
        }
        float res = 0.5f * (acc0 + acc1) + bias[lane];
        res = res > 0.0f ? res : expm1f(res);
        out[(size_t)wave * C + lane] = res;
    } else {
        float acc = 0.0f;
#pragma unroll
        for (int k = 0; k < KN; ++k) {
            float al = (lane < 32) ? lo0[k] * inv0 : lo1[k] * inv1;
            acc = fmaf(al, lds[w][k][lane], acc);
        }
        float o = __shfl_xor(acc, 32);
        if (lane < 32) {
            float res = 0.5f * (acc + o) + bias[lane];
            res = res > 0.0f ? res : expm1f(res);
            out[(size_t)wave * C + lane] = res;
        }
    }
}

// ---------------------------------------------------------------------------
// 4. Fused 2-layer GRU (PyTorch cell math), zero init, seq-first [T,N,32].
//    8 nodes per block, 32 threads per node (thread d owns hidden dim d).
//    Weights stored TRANSPOSED in LDS: wT[i*96 + r] = W[r*32 + i]  (bank-safe)
// ---------------------------------------------------------------------------
__global__ __launch_bounds__(256) void k_gru2(
    const float* __restrict__ x,
    const float* __restrict__ Wih0, const float* __restrict__ Whh0,
    const float* __restrict__ bih0, const float* __restrict__ bhh0,
    const float* __restrict__ Wih1, const float* __restrict__ Whh1,
    const float* __restrict__ bih1, const float* __restrict__ bhh1,
    float* __restrict__ E)
{
    __shared__ float w0i[96 * 32], w0h[96 * 32], w1i[96 * 32], w1h[96 * 32];
    __shared__ float bb[4][96];
    __shared__ float xs[8][32], h0s[8][32], h1s[8][32];

    for (int idx = threadIdx.x; idx < 96 * 32; idx += 256) {
        int r = idx >> 5, c = idx & 31;
        int tr = c * 96 + r;
        w0i[tr] = Wih0[idx]; w0h[tr] = Whh0[idx];
        w1i[tr] = Wih1[idx]; w1h[tr] = Whh1[idx];
    }
    if (threadIdx.x < 96) {
        bb[0][threadIdx.x] = bih0[threadIdx.x];
        bb[1][threadIdx.x] = bhh0[threadIdx.x];
        bb[2][threadIdx.x] = bih1[threadIdx.x];
        bb[3][threadIdx.x] = bhh1[threadIdx.x];
    }
    const int d = threadIdx.x & 31;
    const int nd = threadIdx.x >> 5;
    const int node = blockIdx.x * 8 + nd;
    h0s[nd][d] = 0.0f;
    h1s[nd][d] = 0.0f;
    __syncthreads();

    for (int t = 0; t < Tt; ++t) {
        xs[nd][d] = x[((size_t)t * Nn + node) * 32 + d];
        __syncthreads();

        // ---- layer 0 ----
        float gr_ = bb[0][d], gz_ = bb[0][32 + d], gn_ = bb[0][64 + d];
        float hr_ = bb[1][d], hz_ = bb[1][32 + d], hn_ = bb[1][64 + d];
#pragma unroll 8
        for (int i = 0; i < 32; ++i) {
            float xv = xs[nd][i], hv = h0s[nd][i];
            gr_ = fmaf(xv, w0i[i * 96 + d], gr_);
            gz_ = fmaf(xv, w0i[i * 96 + 32 + d], gz_);
            gn_ = fmaf(xv, w0i[i * 96 + 64 + d], gn_);
            hr_ = fmaf(hv, w0h[i * 96 + d], hr_);
            hz_ = fmaf(hv, w0h[i * 96 + 32 + d], hz_);
            hn_ = fmaf(hv, w0h[i * 96 + 64 + d], hn_);
        }
        float r = 1.0f / (1.0f + expf(-(gr_ + hr_)));
        float z = 1.0f / (1.0f + expf(-(gz_ + hz_)));
        float nn = tanhf(gn_ + r * hn_);
        float h0new = (1.0f - z) * nn + z * h0s[nd][d];
        __syncthreads();
        h0s[nd][d] = h0new;            // also the layer-1 input
        __syncthreads();

        // ---- layer 1 ----
        gr_ = bb[2][d]; gz_ = bb[2][32 + d]; gn_ = bb[2][64 + d];
        hr_ = bb[3][d]; hz_ = bb[3][32 + d]; hn_ = bb[3][64 + d];
#pragma unroll 8
        for (int i = 0; i < 32; ++i) {
            float xv = h0s[nd][i], hv = h1s[nd][i];
            gr_ = fmaf(xv, w1i[i * 96 + d], gr_);
            gz_ = fmaf(xv, w1i[i * 96 + 32 + d], gz_);
            gn_ = fmaf(xv, w1i[i * 96 + 64 + d], gn_);
            hr_ = fmaf(hv, w1h[i * 96 + d], hr_);
            hz_ = fmaf(hv, w1h[i * 96 + 32 + d], hz_);
            hn_ = fmaf(hv, w1h[i * 96 + 64 + d], hn_);
        }
        r = 1.0f / (1.0f + expf(-(gr_ + hr_)));
        z = 1.0f / (1.0f + expf(-(gz_ + hz_)));
        nn = tanhf(gn_ + r * hn_);
        float h1new = (1.0f - z) * nn + z * h1s[nd][d];
        E[((size_t)t * Nn + node) * 32 + d] = h1new;
        __syncthreads();
        h1s[nd][d] = h1new;
        __syncthreads();
    }
}

// ---------------------------------------------------------------------------
// 5. out[row,:] = tanh(in[row,:] @ W2 + b2) @ W3 + b3   (64 -> 64 -> 50)
//    One wave per row, 4 rows per block.
// ---------------------------------------------------------------------------
__global__ __launch_bounds__(256) void k_head(
    const float* __restrict__ in, const float* __restrict__ W2,
    const float* __restrict__ b2, const float* __restrict__ W3,
    const float* __restrict__ b3, float* __restrict__ out, int rows)
{
    __shared__ float xin[4][64], tmp[4][64];
    const int lane = threadIdx.x & 63;
    const int w = threadIdx.x >> 6;
    const int row = blockIdx.x * 4 + w;
    xin[w][lane] = in[(size_t)row * 64 + lane];
    __syncthreads();
    float acc = b2[lane];
#pragma unroll 8
    for (int i = 0; i < 64; ++i)
        acc = fmaf(xin[w][i], W2[i * 64 + lane], acc);
    tmp[w][lane] = tanhf(acc);
    __syncthreads();
    if (lane < 50) {
        float a = b3[lane];
#pragma unroll 8
        for (int j = 0; j < 64; ++j)
            a = fmaf(tmp[w][j], W3[j * 50 + lane], a);
        out[(size_t)row * 50 + lane] = a;
    }
}

// ---------------------------------------------------------------------------
extern "C" void kernel_launch(void* const* d_in, const int* in_sizes, int n_in,
                              void* d_out, int out_size, void* d_ws, size_t ws_size,
                              hipStream_t stream)
{
    const float* x    = (const float*)d_in[0];
    const int*   edge = (const int*)d_in[1];

    const float *g1_Wl = (const float*)d_in[2],  *g1_bl = (const float*)d_in[3];
    const float *g1_Wr = (const float*)d_in[4],  *g1_br = (const float*)d_in[5];
    const float *g1_att= (const float*)d_in[6],  *g1_b  = (const float*)d_in[7];
    const float *g2_Wl = (const float*)d_in[8],  *g2_bl = (const float*)d_in[9];
    const float *g2_Wr = (const float*)d_in[10], *g2_br = (const float*)d_in[11];
    const float *g2_att= (const float*)d_in[12], *g2_b  = (const float*)d_in[13];
    const float *r1_Wl = (const float*)d_in[14], *r1_bl = (const float*)d_in[15];
    const float *r1_Wr = (const float*)d_in[16], *r1_br = (const float*)d_in[17];
    const float *r1_att= (const float*)d_in[18], *r1_b  = (const float*)d_in[19];
    const float *f1_Wl = (const float*)d_in[20], *f1_bl = (const float*)d_in[21];
    const float *f1_Wr = (const float*)d_in[22], *f1_br = (const float*)d_in[23];
    const float *f1_att= (const float*)d_in[24], *f1_b  = (const float*)d_in[25];
    const float *gru0_Wih = (const float*)d_in[26], *gru0_Whh = (const float*)d_in[27];
    const float *gru0_bih = (const float*)d_in[28], *gru0_bhh = (const float*)d_in[29];
    const float *gru1_Wih = (const float*)d_in[30], *gru1_Whh = (const float*)d_in[31];
    const float *gru1_bih = (const float*)d_in[32], *gru1_bhh = (const float*)d_in[33];
    const float *rec2_W = (const float*)d_in[34], *rec2_b = (const float*)d_in[35];
    const float *rec3_W = (const float*)d_in[36], *rec3_b = (const float*)d_in[37];
    const float *fore3_W= (const float*)d_in[38], *fore3_b= (const float*)d_in[39];

    // workspace layout
    char* ws = (char*)d_ws;
    int*   srcs = (int*)ws;                              // 32*16*1024 ints (2 MB)
    float* buf1 = (float*)(ws + (4u << 20));             // [32768,128] 16 MB
    float* buf2 = buf1 + (size_t)32768 * 128;            // [32768,128] 16 MB
    float* buf3 = buf2 + (size_t)32768 * 128;            // [32768,64]   8 MB
    float* buf4 = buf3 + (size_t)32768 * 64;             // [32768,32]   4 MB

    float* recon = (float*)d_out;                        // [31,1024,50]
    float* fore  = recon + (size_t)31 * 1024 * 50;       // [31,1024,50]
    float* E     = fore  + (size_t)31 * 1024 * 50;       // [32,1024,32]

    // 1. adjacency -> source lists
    k_srcs<<<(Tt * Nn) / 256, 256, 0, stream>>>(edge, srcs);

    // 2. GAT g1 (64 -> 64, H*C = 128)
    k_lin<<<dim3(16384), dim3(128, 2), 0, stream>>>(x, g1_Wl, g1_bl, buf1, 32768, 64, 128);
    k_lin<<<dim3(16384), dim3(128, 2), 0, stream>>>(x, g1_Wr, g1_br, buf2, 32768, 64, 128);
    k_gat<64><<<8192, 256, 0, stream>>>(buf1, buf2, srcs, g1_att, g1_b, buf3, 32768);

    // 3. GAT g2 (64 -> 32, H*C = 64)
    k_lin<<<dim3(8192), dim3(64, 4), 0, stream>>>(buf3, g2_Wl, g2_bl, buf1, 32768, 64, 64);
    k_lin<<<dim3(8192), dim3(64, 4), 0, stream>>>(buf3, g2_Wr, g2_br, buf2, 32768, 64, 64);
    k_gat<32><<<8192, 256, 0, stream>>>(buf1, buf2, srcs, g2_att, g2_b, buf4, 32768);

    // 4. two stacked GRUs -> E (written straight into d_out)
    k_gru2<<<Nn / 8, 256, 0, stream>>>(buf4,
        gru0_Wih, gru0_Whh, gru0_bih, gru0_bhh,
        gru1_Wih, gru1_Whh, gru1_bih, gru1_bhh, E);

    // 5. reconstruct path: GAT r1 on E[1:], then tanh(@rec2)@rec3
    k_lin<<<dim3(15872), dim3(128, 2), 0, stream>>>(E + (size_t)Nn * 32, r1_Wl, r1_bl, buf1, 31744, 32, 128);
    k_lin<<<dim3(15872), dim3(128, 2), 0, stream>>>(E + (size_t)Nn * 32, r1_Wr, r1_br, buf2, 31744, 32, 128);
    k_gat<64><<<7936, 256, 0, stream>>>(buf1, buf2, srcs + KN * Nn, r1_att, r1_b, buf3, 31744);
    k_head<<<7936, 256, 0, stream>>>(buf3, rec2_W, rec2_b, rec3_W, rec3_b, recon, 31744);

    // 6. forecast path: GAT f1 on E[:-1], then tanh(@rec2)@fore3
    k_lin<<<dim3(15872), dim3(128, 2), 0, stream>>>(E, f1_Wl, f1_bl, buf1, 31744, 32, 128);
    k_lin<<<dim3(15872), dim3(128, 2), 0, stream>>>(E, f1_Wr, f1_br, buf2, 31744, 32, 128);
    k_gat<64><<<7936, 256, 0, stream>>>(buf1, buf2, srcs, f1_att, f1_b, buf3, 31744);
    k_head<<<7936, 256, 0, stream>>>(buf3, rec2_W, rec2_b, fore3_W, fore3_b, fore, 31744);

    (void)in_sizes; (void)n_in; (void)out_size; (void)ws_size;
}

// Round 2
// 765.152 us; speedup vs baseline: 1.5232x; 1.5232x over previous
//
#include <hip/hip_runtime.h>
#include <math.h>

static constexpr int Tt = 32;
static constexpr int Nn = 1024;
static constexpr int KN = 16;   // K + self

// ---------------------------------------------------------------------------
// 1. Recover source indices (order-free): for each (t,tgt) column, the 15
//    sources with edge[t,src,tgt]==1 land in slots 0..14 (any order — GAT is
//    permutation-invariant), slot 15 = self loop.
//    One 1024-thread block per (t, 64-target stripe); 16 s-groups per column.
// ---------------------------------------------------------------------------
__global__ __launch_bounds__(1024) void k_srcs(const int* __restrict__ edge,
                                               int* __restrict__ srcs)
{
    __shared__ int cnt[64];
    const int t    = blockIdx.x >> 4;          // 0..31
    const int tgt0 = (blockIdx.x & 15) << 6;   // 0,64,...,960
    const int x = threadIdx.x & 63;            // target lane
    const int y = threadIdx.x >> 6;            // s-group 0..15
    if (threadIdx.x < 64) cnt[threadIdx.x] = 0;
    __syncthreads();

    const int tgt = tgt0 + x;
    const int* e = edge + (size_t)t * Nn * Nn + tgt;
    const int s0 = y * 64;

    for (int i0 = 0; i0 < 64; i0 += 16) {
        int v[16];
#pragma unroll
        for (int j = 0; j < 16; ++j)
            v[j] = e[(size_t)(s0 + i0 + j) * Nn];
#pragma unroll
        for (int j = 0; j < 16; ++j) {
            if (v[j] != 0) {
                int slot = atomicAdd(&cnt[x], 1);
                if (slot < KN - 1)
                    srcs[(t * KN + slot) * Nn + tgt] = s0 + i0 + j;
            }
        }
    }
    if (y == 0) srcs[(t * KN + (KN - 1)) * Nn + tgt] = tgt;
}

// ---------------------------------------------------------------------------
// 2. Fused dual linear: Yl = X@Wl + bl, Yr = X@Wr + br (shared X reads).
//    blockDim = (fo, 256/fo)
// ---------------------------------------------------------------------------
__global__ void k_lin2(const float* __restrict__ X,
                       const float* __restrict__ Wl, const float* __restrict__ bl,
                       const float* __restrict__ Wr, const float* __restrict__ br,
                       float* __restrict__ Yl, float* __restrict__ Yr,
                       int rows, int fi, int fo)
{
    int col = threadIdx.x;
    int row = blockIdx.x * blockDim.y + threadIdx.y;
    if (row >= rows) return;
    float accl = bl[col], accr = br[col];
    const float* xr = X + (size_t)row * fi;
    for (int i = 0; i < fi; ++i) {
        float xv = xr[i];
        accl = fmaf(xv, Wl[i * fo + col], accl);
        accr = fmaf(xv, Wr[i * fo + col], accr);
    }
    Yl[(size_t)row * fo + col] = accl;
    Yr[(size_t)row * fo + col] = accr;
}

// ---------------------------------------------------------------------------
// 3. GATv2 attention + aggregate + mean-heads + bias + ELU.
//    One wave per (t, target). H=2 heads fixed. C = per-head channels.
// ---------------------------------------------------------------------------
template <int C>
__global__ __launch_bounds__(256) void k_gat(
    const float* __restrict__ gl, const float* __restrict__ gr,
    const int* __restrict__ srcs, const float* __restrict__ att,
    const float* __restrict__ bias, float* __restrict__ out, int rows)
{
    constexpr int HC = 2 * C;
    __shared__ float lds[4][KN][HC];
    const int lane = threadIdx.x & 63;
    const int w = threadIdx.x >> 6;
    const int wave = blockIdx.x * 4 + w;
    if (wave >= rows) return;
    const int t = wave >> 10;
    const int n = wave & (Nn - 1);

    float lo0[KN], lo1[KN];

    if (C == 64) {
        const float grl0 = gr[(size_t)wave * HC + lane];
        const float grl1 = gr[(size_t)wave * HC + 64 + lane];
        const float a0 = att[lane], a1 = att[64 + lane];
#pragma unroll
        for (int k = 0; k < KN; ++k) {
            int s = srcs[(t * KN + k) * Nn + n];
            const float* gsr = gl + ((size_t)t * Nn + s) * HC;
            float g0 = gsr[lane], g1 = gsr[64 + lane];
            lds[w][k][lane] = g0;
            lds[w][k][64 + lane] = g1;
            float e0 = g0 + grl0; e0 = e0 > 0.0f ? e0 : 0.2f * e0;
            float e1 = g1 + grl1; e1 = e1 > 0.0f ? e1 : 0.2f * e1;
            float p0 = e0 * a0, p1 = e1 * a1;
#pragma unroll
            for (int m = 1; m < 64; m <<= 1) {
                p0 += __shfl_xor(p0, m);
                p1 += __shfl_xor(p1, m);
            }
            lo0[k] = p0; lo1[k] = p1;
        }
    } else {
        const float grl = gr[(size_t)wave * HC + lane];
        const float a = att[lane];
#pragma unroll
        for (int k = 0; k < KN; ++k) {
            int s = srcs[(t * KN + k) * Nn + n];
            const float* gsr = gl + ((size_t)t * Nn + s) * HC;
            float g = gsr[lane];
            lds[w][k][lane] = g;
            float e = g + grl; e = e > 0.0f ? e : 0.2f * e;
            float p = e * a;
#pragma unroll
            for (int m = 1; m < 32; m <<= 1) p += __shfl_xor(p, m);
            float o = __shfl_xor(p, 32);
            lo0[k] = (lane < 32) ? p : o;
            lo1[k] = (lane < 32) ? o : p;
        }
    }

    __syncthreads();

    float m0 = lo0[0], m1 = lo1[0];
#pragma unroll
    for (int k = 1; k < KN; ++k) { m0 = fmaxf(m0, lo0[k]); m1 = fmaxf(m1, lo1[k]); }
    float s0 = 0.0f, s1 = 0.0f;
#pragma unroll
    for (int k = 0; k < KN; ++k) {
        lo0[k] = expf(lo0[k] - m0); s0 += lo0[k];
        lo1[k] = expf(lo1[k] - m1); s1 += lo1[k];
    }
    const float inv0 = 1.0f / s0, inv1 = 1.0f / s1;

    if (C == 64) {
        float acc0 = 0.0f, acc1 = 0.0f;
#pragma unroll
        for (int k = 0; k < KN; ++k) {
            acc0 = fmaf(lo0[k] * inv0, lds[w][k][lane], acc0);
            acc1 = fmaf(lo1[k] * inv1, lds[w][k][64 + lane], acc1);
        }
        float res = 0.5f * (acc0 + acc1) + bias[lane];
        res = res > 0.0f ? res : expm1f(res);
        out[(size_t)wave * C + lane] = res;
    } else {
        float acc = 0.0f;
#pragma unroll
        for (int k = 0; k < KN; ++k) {
            float al = (lane < 32) ? lo0[k] * inv0 : lo1[k] * inv1;
            acc = fmaf(al, lds[w][k][lane], acc);
        }
        float o = __shfl_xor(acc, 32);
        if (lane < 32) {
            float res = 0.5f * (acc + o) + bias[lane];
            res = res > 0.0f ? res : expm1f(res);
            out[(size_t)wave * C + lane] = res;
        }
    }
}

// ---------------------------------------------------------------------------
// 4. Fused 2-layer GRU (PyTorch cell math), zero init, seq-first [T,N,32].
// ---------------------------------------------------------------------------
__global__ __launch_bounds__(256) void k_gru2(
    const float* __restrict__ x,
    const float* __restrict__ Wih0, const float* __restrict__ Whh0,
    const float* __restrict__ bih0, const float* __restrict__ bhh0,
    const float* __restrict__ Wih1, const float* __restrict__ Whh1,
    const float* __restrict__ bih1, const float* __restrict__ bhh1,
    float* __restrict__ E)
{
    __shared__ float w0i[96 * 32], w0h[96 * 32], w1i[96 * 32], w1h[96 * 32];
    __shared__ float bb[4][96];
    __shared__ float xs[8][32], h0s[8][32], h1s[8][32];

    for (int idx = threadIdx.x; idx < 96 * 32; idx += 256) {
        int r = idx >> 5, c = idx & 31;
        int tr = c * 96 + r;
        w0i[tr] = Wih0[idx]; w0h[tr] = Whh0[idx];
        w1i[tr] = Wih1[idx]; w1h[tr] = Whh1[idx];
    }
    if (threadIdx.x < 96) {
        bb[0][threadIdx.x] = bih0[threadIdx.x];
        bb[1][threadIdx.x] = bhh0[threadIdx.x];
        bb[2][threadIdx.x] = bih1[threadIdx.x];
        bb[3][threadIdx.x] = bhh1[threadIdx.x];
    }
    const int d = threadIdx.x & 31;
    const int nd = threadIdx.x >> 5;
    const int node = blockIdx.x * 8 + nd;
    h0s[nd][d] = 0.0f;
    h1s[nd][d] = 0.0f;
    __syncthreads();

    for (int t = 0; t < Tt; ++t) {
        xs[nd][d] = x[((size_t)t * Nn + node) * 32 + d];
        __syncthreads();

        float gr_ = bb[0][d], gz_ = bb[0][32 + d], gn_ = bb[0][64 + d];
        float hr_ = bb[1][d], hz_ = bb[1][32 + d], hn_ = bb[1][64 + d];
#pragma unroll 8
        for (int i = 0; i < 32; ++i) {
            float xv = xs[nd][i], hv = h0s[nd][i];
            gr_ = fmaf(xv, w0i[i * 96 + d], gr_);
            gz_ = fmaf(xv, w0i[i * 96 + 32 + d], gz_);
            gn_ = fmaf(xv, w0i[i * 96 + 64 + d], gn_);
            hr_ = fmaf(hv, w0h[i * 96 + d], hr_);
            hz_ = fmaf(hv, w0h[i * 96 + 32 + d], hz_);
            hn_ = fmaf(hv, w0h[i * 96 + 64 + d], hn_);
        }
        float r = 1.0f / (1.0f + expf(-(gr_ + hr_)));
        float z = 1.0f / (1.0f + expf(-(gz_ + hz_)));
        float nn = tanhf(gn_ + r * hn_);
        float h0new = (1.0f - z) * nn + z * h0s[nd][d];
        __syncthreads();
        h0s[nd][d] = h0new;
        __syncthreads();

        gr_ = bb[2][d]; gz_ = bb[2][32 + d]; gn_ = bb[2][64 + d];
        hr_ = bb[3][d]; hz_ = bb[3][32 + d]; hn_ = bb[3][64 + d];
#pragma unroll 8
        for (int i = 0; i < 32; ++i) {
            float xv = h0s[nd][i], hv = h1s[nd][i];
            gr_ = fmaf(xv, w1i[i * 96 + d], gr_);
            gz_ = fmaf(xv, w1i[i * 96 + 32 + d], gz_);
            gn_ = fmaf(xv, w1i[i * 96 + 64 + d], gn_);
            hr_ = fmaf(hv, w1h[i * 96 + d], hr_);
            hz_ = fmaf(hv, w1h[i * 96 + 32 + d], hz_);
            hn_ = fmaf(hv, w1h[i * 96 + 64 + d], hn_);
        }
        r = 1.0f / (1.0f + expf(-(gr_ + hr_)));
        z = 1.0f / (1.0f + expf(-(gz_ + hz_)));
        nn = tanhf(gn_ + r * hn_);
        float h1new = (1.0f - z) * nn + z * h1s[nd][d];
        E[((size_t)t * Nn + node) * 32 + d] = h1new;
        __syncthreads();
        h1s[nd][d] = h1new;
        __syncthreads();
    }
}

// ---------------------------------------------------------------------------
// 5. out[row,:] = tanh(in[row,:] @ W2 + b2) @ W3 + b3   (64 -> 64 -> 50)
// ---------------------------------------------------------------------------
__global__ __launch_bounds__(256) void k_head(
    const float* __restrict__ in, const float* __restrict__ W2,
    const float* __restrict__ b2, const float* __restrict__ W3,
    const float* __restrict__ b3, float* __restrict__ out, int rows)
{
    __shared__ float xin[4][64], tmp[4][64];
    const int lane = threadIdx.x & 63;
    const int w = threadIdx.x >> 6;
    const int row = blockIdx.x * 4 + w;
    xin[w][lane] = in[(size_t)row * 64 + lane];
    __syncthreads();
    float acc = b2[lane];
#pragma unroll 8
    for (int i = 0; i < 64; ++i)
        acc = fmaf(xin[w][i], W2[i * 64 + lane], acc);
    tmp[w][lane] = tanhf(acc);
    __syncthreads();
    if (lane < 50) {
        float a = b3[lane];
#pragma unroll 8
        for (int j = 0; j < 64; ++j)
            a = fmaf(tmp[w][j], W3[j * 50 + lane], a);
        out[(size_t)row * 50 + lane] = a;
    }
}

// ---------------------------------------------------------------------------
extern "C" void kernel_launch(void* const* d_in, const int* in_sizes, int n_in,
                              void* d_out, int out_size, void* d_ws, size_t ws_size,
                              hipStream_t stream)
{
    const float* x    = (const float*)d_in[0];
    const int*   edge = (const int*)d_in[1];

    const float *g1_Wl = (const float*)d_in[2],  *g1_bl = (const float*)d_in[3];
    const float *g1_Wr = (const float*)d_in[4],  *g1_br = (const float*)d_in[5];
    const float *g1_att= (const float*)d_in[6],  *g1_b  = (const float*)d_in[7];
    const float *g2_Wl = (const float*)d_in[8],  *g2_bl = (const float*)d_in[9];
    const float *g2_Wr = (const float*)d_in[10], *g2_br = (const float*)d_in[11];
    const float *g2_att= (const float*)d_in[12], *g2_b  = (const float*)d_in[13];
    const float *r1_Wl = (const float*)d_in[14], *r1_bl = (const float*)d_in[15];
    const float *r1_Wr = (const float*)d_in[16], *r1_br = (const float*)d_in[17];
    const float *r1_att= (const float*)d_in[18], *r1_b  = (const float*)d_in[19];
    const float *f1_Wl = (const float*)d_in[20], *f1_bl = (const float*)d_in[21];
    const float *f1_Wr = (const float*)d_in[22], *f1_br = (const float*)d_in[23];
    const float *f1_att= (const float*)d_in[24], *f1_b  = (const float*)d_in[25];
    const float *gru0_Wih = (const float*)d_in[26], *gru0_Whh = (const float*)d_in[27];
    const float *gru0_bih = (const float*)d_in[28], *gru0_bhh = (const float*)d_in[29];
    const float *gru1_Wih = (const float*)d_in[30], *gru1_Whh = (const float*)d_in[31];
    const float *gru1_bih = (const float*)d_in[32], *gru1_bhh = (const float*)d_in[33];
    const float *rec2_W = (const float*)d_in[34], *rec2_b = (const float*)d_in[35];
    const float *rec3_W = (const float*)d_in[36], *rec3_b = (const float*)d_in[37];
    const float *fore3_W= (const float*)d_in[38], *fore3_b= (const float*)d_in[39];

    // workspace layout
    char* ws = (char*)d_ws;
    int*   srcs = (int*)ws;                              // 32*16*1024 ints (2 MB)
    float* buf1 = (float*)(ws + (4u << 20));             // [32768,128] 16 MB
    float* buf2 = buf1 + (size_t)32768 * 128;            // [32768,128] 16 MB
    float* buf3 = buf2 + (size_t)32768 * 128;            // [32768,64]   8 MB
    float* buf4 = buf3 + (size_t)32768 * 64;             // [32768,32]   4 MB

    float* recon = (float*)d_out;                        // [31,1024,50]
    float* fore  = recon + (size_t)31 * 1024 * 50;       // [31,1024,50]
    float* E     = fore  + (size_t)31 * 1024 * 50;       // [32,1024,32]

    // 1. adjacency -> source lists (parallel scan, order-free slots)
    k_srcs<<<Tt * (Nn / 64), 1024, 0, stream>>>(edge, srcs);

    // 2. GAT g1 (64 -> 64, H*C = 128)
    k_lin2<<<dim3(16384), dim3(128, 2), 0, stream>>>(x, g1_Wl, g1_bl, g1_Wr, g1_br, buf1, buf2, 32768, 64, 128);
    k_gat<64><<<8192, 256, 0, stream>>>(buf1, buf2, srcs, g1_att, g1_b, buf3, 32768);

    // 3. GAT g2 (64 -> 32, H*C = 64)
    k_lin2<<<dim3(8192), dim3(64, 4), 0, stream>>>(buf3, g2_Wl, g2_bl, g2_Wr, g2_br, buf1, buf2, 32768, 64, 64);
    k_gat<32><<<8192, 256, 0, stream>>>(buf1, buf2, srcs, g2_att, g2_b, buf4, 32768);

    // 4. two stacked GRUs -> E (written straight into d_out)
    k_gru2<<<Nn / 8, 256, 0, stream>>>(buf4,
        gru0_Wih, gru0_Whh, gru0_bih, gru0_bhh,
        gru1_Wih, gru1_Whh, gru1_bih, gru1_bhh, E);

    // 5. reconstruct path: GAT r1 on E[1:], then tanh(@rec2)@rec3
    k_lin2<<<dim3(15872), dim3(128, 2), 0, stream>>>(E + (size_t)Nn * 32, r1_Wl, r1_bl, r1_Wr, r1_br, buf1, buf2, 31744, 32, 128);
    k_gat<64><<<7936, 256, 0, stream>>>(buf1, buf2, srcs + KN * Nn, r1_att, r1_b, buf3, 31744);
    k_head<<<7936, 256, 0, stream>>>(buf3, rec2_W, rec2_b, rec3_W, rec3_b, recon, 31744);

    // 6. forecast path: GAT f1 on E[:-1], then tanh(@rec2)@fore3
    k_lin2<<<dim3(15872), dim3(128, 2), 0, stream>>>(E, f1_Wl, f1_bl, f1_Wr, f1_br, buf1, buf2, 31744, 32, 128);
    k_gat<64><<<7936, 256, 0, stream>>>(buf1, buf2, srcs, f1_att, f1_b, buf3, 31744);
    k_head<<<7936, 256, 0, stream>>>(buf3, rec2_W, rec2_b, fore3_W, fore3_b, fore, 31744);

    (void)in_sizes; (void)n_in; (void)out_size; (void)ws_size;
}

// Round 3
// 533.903 us; speedup vs baseline: 2.1830x; 1.4331x over previous
//
#include <hip/hip_runtime.h>
#include <math.h>

static constexpr int Tt = 32;
static constexpr int Nn = 1024;
static constexpr int KN = 16;   // K + self

// ---------------------------------------------------------------------------
// 1. Recover source indices (order-free): for each (t,tgt) column, the 15
//    sources with edge[t,src,tgt]==1 land in slots 0..14 (any order — GAT is
//    permutation-invariant), slot 15 = self loop.
// ---------------------------------------------------------------------------
__global__ __launch_bounds__(1024) void k_srcs(const int* __restrict__ edge,
                                               int* __restrict__ srcs)
{
    __shared__ int cnt[64];
    const int t    = blockIdx.x >> 4;          // 0..31
    const int tgt0 = (blockIdx.x & 15) << 6;   // 0,64,...,960
    const int x = threadIdx.x & 63;            // target lane
    const int y = threadIdx.x >> 6;            // s-group 0..15
    if (threadIdx.x < 64) cnt[threadIdx.x] = 0;
    __syncthreads();

    const int tgt = tgt0 + x;
    const int* e = edge + (size_t)t * Nn * Nn + tgt;
    const int s0 = y * 64;

    for (int i0 = 0; i0 < 64; i0 += 16) {
        int v[16];
#pragma unroll
        for (int j = 0; j < 16; ++j)
            v[j] = e[(size_t)(s0 + i0 + j) * Nn];
#pragma unroll
        for (int j = 0; j < 16; ++j) {
            if (v[j] != 0) {
                int slot = atomicAdd(&cnt[x], 1);
                if (slot < KN - 1)
                    srcs[(t * KN + slot) * Nn + tgt] = s0 + i0 + j;
            }
        }
    }
    if (y == 0) srcs[(t * KN + (KN - 1)) * Nn + tgt] = tgt;
}

// ---------------------------------------------------------------------------
// 2. Register-blocked dual linear: Yl = X@Wl + bl, Yr = X@Wr + br.
//    Block = 256 threads, covers BR rows. Each thread: 8 rows x 2 cols x 2
//    mats = 32 accumulators. X tile staged in LDS (reads are wave-uniform
//    broadcasts); W read coalesced from global (L1/L2-resident).
// ---------------------------------------------------------------------------
template <int FI, int FO>
__global__ __launch_bounds__(256) void k_lin2t(
    const float* __restrict__ X,
    const float* __restrict__ Wl, const float* __restrict__ bl,
    const float* __restrict__ Wr, const float* __restrict__ br,
    float* __restrict__ Yl, float* __restrict__ Yr, int rows)
{
    constexpr int HC = FO / 2;          // thread's cols: c and c+HC
    constexpr int RG = 256 / HC;        // row-groups per block
    constexpr int R  = 8;               // rows per thread
    constexpr int BR = RG * R;          // rows per block
    constexpr int F4 = FI / 4;
    __shared__ float xs[BR][FI];

    const int tid  = threadIdx.x;
    const int c    = tid % HC;
    const int g    = tid / HC;
    const int row0 = blockIdx.x * BR;

    // stage X tile, coalesced float4
#pragma unroll
    for (int idx = tid; idx < BR * F4; idx += 256) {
        int r = idx / F4, q = idx % F4;
        reinterpret_cast<float4*>(&xs[r][0])[q] =
            reinterpret_cast<const float4*>(X + (size_t)(row0 + r) * FI)[q];
    }
    __syncthreads();

    float al0[R], al1[R], ar0[R], ar1[R];
    const float bl0 = bl[c], bl1 = bl[c + HC], br0 = br[c], br1 = br[c + HC];
#pragma unroll
    for (int r = 0; r < R; ++r) { al0[r] = bl0; al1[r] = bl1; ar0[r] = br0; ar1[r] = br1; }

    const int rb = g * R;
#pragma unroll
    for (int i0 = 0; i0 < FI; i0 += 4) {
        float4 xv[R];
#pragma unroll
        for (int r = 0; r < R; ++r)
            xv[r] = *reinterpret_cast<const float4*>(&xs[rb + r][i0]);
#pragma unroll
        for (int j = 0; j < 4; ++j) {
            const float wl0 = Wl[(i0 + j) * FO + c];
            const float wl1 = Wl[(i0 + j) * FO + c + HC];
            const float wr0 = Wr[(i0 + j) * FO + c];
            const float wr1 = Wr[(i0 + j) * FO + c + HC];
#pragma unroll
            for (int r = 0; r < R; ++r) {
                const float xx = (&xv[r].x)[j];
                al0[r] = fmaf(xx, wl0, al0[r]);
                al1[r] = fmaf(xx, wl1, al1[r]);
                ar0[r] = fmaf(xx, wr0, ar0[r]);
                ar1[r] = fmaf(xx, wr1, ar1[r]);
            }
        }
    }
#pragma unroll
    for (int r = 0; r < R; ++r) {
        const size_t ro = (size_t)(row0 + rb + r) * FO;
        Yl[ro + c]      = al0[r];
        Yl[ro + c + HC] = al1[r];
        Yr[ro + c]      = ar0[r];
        Yr[ro + c + HC] = ar1[r];
    }
}

// ---------------------------------------------------------------------------
// 3. GATv2 attention + aggregate + mean-heads + bias + ELU.
//    One wave per (t, target). H=2 heads fixed. C = per-head channels.
// ---------------------------------------------------------------------------
template <int C>
__global__ __launch_bounds__(256) void k_gat(
    const float* __restrict__ gl, const float* __restrict__ gr,
    const int* __restrict__ srcs, const float* __restrict__ att,
    const float* __restrict__ bias, float* __restrict__ out, int rows)
{
    constexpr int HC = 2 * C;
    __shared__ float lds[4][KN][HC];
    const int lane = threadIdx.x & 63;
    const int w = threadIdx.x >> 6;
    const int wave = blockIdx.x * 4 + w;
    if (wave >= rows) return;
    const int t = wave >> 10;
    const int n = wave & (Nn - 1);

    float lo0[KN], lo1[KN];

    if (C == 64) {
        const float grl0 = gr[(size_t)wave * HC + lane];
        const float grl1 = gr[(size_t)wave * HC + 64 + lane];
        const float a0 = att[lane], a1 = att[64 + lane];
#pragma unroll
        for (int k = 0; k < KN; ++k) {
            int s = srcs[(t * KN + k) * Nn + n];
            const float* gsr = gl + ((size_t)t * Nn + s) * HC;
            float g0 = gsr[lane], g1 = gsr[64 + lane];
            lds[w][k][lane] = g0;
            lds[w][k][64 + lane] = g1;
            float e0 = g0 + grl0; e0 = e0 > 0.0f ? e0 : 0.2f * e0;
            float e1 = g1 + grl1; e1 = e1 > 0.0f ? e1 : 0.2f * e1;
            float p0 = e0 * a0, p1 = e1 * a1;
#pragma unroll
            for (int m = 1; m < 64; m <<= 1) {
                p0 += __shfl_xor(p0, m);
                p1 += __shfl_xor(p1, m);
            }
            lo0[k] = p0; lo1[k] = p1;
        }
    } else {
        const float grl = gr[(size_t)wave * HC + lane];
        const float a = att[lane];
#pragma unroll
        for (int k = 0; k < KN; ++k) {
            int s = srcs[(t * KN + k) * Nn + n];
            const float* gsr = gl + ((size_t)t * Nn + s) * HC;
            float g = gsr[lane];
            lds[w][k][lane] = g;
            float e = g + grl; e = e > 0.0f ? e : 0.2f * e;
            float p = e * a;
#pragma unroll
            for (int m = 1; m < 32; m <<= 1) p += __shfl_xor(p, m);
            float o = __shfl_xor(p, 32);
            lo0[k] = (lane < 32) ? p : o;
            lo1[k] = (lane < 32) ? o : p;
        }
    }

    __syncthreads();

    float m0 = lo0[0], m1 = lo1[0];
#pragma unroll
    for (int k = 1; k < KN; ++k) { m0 = fmaxf(m0, lo0[k]); m1 = fmaxf(m1, lo1[k]); }
    float s0 = 0.0f, s1 = 0.0f;
#pragma unroll
    for (int k = 0; k < KN; ++k) {
        lo0[k] = expf(lo0[k] - m0); s0 += lo0[k];
        lo1[k] = expf(lo1[k] - m1); s1 += lo1[k];
    }
    const float inv0 = 1.0f / s0, inv1 = 1.0f / s1;

    if (C == 64) {
        float acc0 = 0.0f, acc1 = 0.0f;
#pragma unroll
        for (int k = 0; k < KN; ++k) {
            acc0 = fmaf(lo0[k] * inv0, lds[w][k][lane], acc0);
            acc1 = fmaf(lo1[k] * inv1, lds[w][k][64 + lane], acc1);
        }
        float res = 0.5f * (acc0 + acc1) + bias[lane];
        res = res > 0.0f ? res : expm1f(res);
        out[(size_t)wave * C + lane] = res;
    } else {
        float acc = 0.0f;
#pragma unroll
        for (int k = 0; k < KN; ++k) {
            float al = (lane < 32) ? lo0[k] * inv0 : lo1[k] * inv1;
            acc = fmaf(al, lds[w][k][lane], acc);
        }
        float o = __shfl_xor(acc, 32);
        if (lane < 32) {
            float res = 0.5f * (acc + o) + bias[lane];
            res = res > 0.0f ? res : expm1f(res);
            out[(size_t)wave * C + lane] = res;
        }
    }
}

// ---------------------------------------------------------------------------
// 4. Fused 2-layer GRU (PyTorch cell math), zero init, seq-first [T,N,32].
// ---------------------------------------------------------------------------
__global__ __launch_bounds__(256) void k_gru2(
    const float* __restrict__ x,
    const float* __restrict__ Wih0, const float* __restrict__ Whh0,
    const float* __restrict__ bih0, const float* __restrict__ bhh0,
    const float* __restrict__ Wih1, const float* __restrict__ Whh1,
    const float* __restrict__ bih1, const float* __restrict__ bhh1,
    float* __restrict__ E)
{
    __shared__ float w0i[96 * 32], w0h[96 * 32], w1i[96 * 32], w1h[96 * 32];
    __shared__ float bb[4][96];
    __shared__ float xs[8][32], h0s[8][32], h1s[8][32];

    for (int idx = threadIdx.x; idx < 96 * 32; idx += 256) {
        int r = idx >> 5, c = idx & 31;
        int tr = c * 96 + r;
        w0i[tr] = Wih0[idx]; w0h[tr] = Whh0[idx];
        w1i[tr] = Wih1[idx]; w1h[tr] = Whh1[idx];
    }
    if (threadIdx.x < 96) {
        bb[0][threadIdx.x] = bih0[threadIdx.x];
        bb[1][threadIdx.x] = bhh0[threadIdx.x];
        bb[2][threadIdx.x] = bih1[threadIdx.x];
        bb[3][threadIdx.x] = bhh1[threadIdx.x];
    }
    const int d = threadIdx.x & 31;
    const int nd = threadIdx.x >> 5;
    const int node = blockIdx.x * 8 + nd;
    h0s[nd][d] = 0.0f;
    h1s[nd][d] = 0.0f;
    __syncthreads();

    for (int t = 0; t < Tt; ++t) {
        xs[nd][d] = x[((size_t)t * Nn + node) * 32 + d];
        __syncthreads();

        float gr_ = bb[0][d], gz_ = bb[0][32 + d], gn_ = bb[0][64 + d];
        float hr_ = bb[1][d], hz_ = bb[1][32 + d], hn_ = bb[1][64 + d];
#pragma unroll 8
        for (int i = 0; i < 32; ++i) {
            float xv = xs[nd][i], hv = h0s[nd][i];
            gr_ = fmaf(xv, w0i[i * 96 + d], gr_);
            gz_ = fmaf(xv, w0i[i * 96 + 32 + d], gz_);
            gn_ = fmaf(xv, w0i[i * 96 + 64 + d], gn_);
            hr_ = fmaf(hv, w0h[i * 96 + d], hr_);
            hz_ = fmaf(hv, w0h[i * 96 + 32 + d], hz_);
            hn_ = fmaf(hv, w0h[i * 96 + 64 + d], hn_);
        }
        float r = 1.0f / (1.0f + expf(-(gr_ + hr_)));
        float z = 1.0f / (1.0f + expf(-(gz_ + hz_)));
        float nn = tanhf(gn_ + r * hn_);
        float h0new = (1.0f - z) * nn + z * h0s[nd][d];
        __syncthreads();
        h0s[nd][d] = h0new;
        __syncthreads();

        gr_ = bb[2][d]; gz_ = bb[2][32 + d]; gn_ = bb[2][64 + d];
        hr_ = bb[3][d]; hz_ = bb[3][32 + d]; hn_ = bb[3][64 + d];
#pragma unroll 8
        for (int i = 0; i < 32; ++i) {
            float xv = h0s[nd][i], hv = h1s[nd][i];
            gr_ = fmaf(xv, w1i[i * 96 + d], gr_);
            gz_ = fmaf(xv, w1i[i * 96 + 32 + d], gz_);
            gn_ = fmaf(xv, w1i[i * 96 + 64 + d], gn_);
            hr_ = fmaf(hv, w1h[i * 96 + d], hr_);
            hz_ = fmaf(hv, w1h[i * 96 + 32 + d], hz_);
            hn_ = fmaf(hv, w1h[i * 96 + 64 + d], hn_);
        }
        r = 1.0f / (1.0f + expf(-(gr_ + hr_)));
        z = 1.0f / (1.0f + expf(-(gz_ + hz_)));
        nn = tanhf(gn_ + r * hn_);
        float h1new = (1.0f - z) * nn + z * h1s[nd][d];
        E[((size_t)t * Nn + node) * 32 + d] = h1new;
        __syncthreads();
        h1s[nd][d] = h1new;
        __syncthreads();
    }
}

// ---------------------------------------------------------------------------
// 5. out[row,:] = tanh(in[row,:] @ W2 + b2) @ W3 + b3   (64 -> 64 -> 50)
// ---------------------------------------------------------------------------
__global__ __launch_bounds__(256) void k_head(
    const float* __restrict__ in, const float* __restrict__ W2,
    const float* __restrict__ b2, const float* __restrict__ W3,
    const float* __restrict__ b3, float* __restrict__ out, int rows)
{
    __shared__ float xin[4][64], tmp[4][64];
    const int lane = threadIdx.x & 63;
    const int w = threadIdx.x >> 6;
    const int row = blockIdx.x * 4 + w;
    xin[w][lane] = in[(size_t)row * 64 + lane];
    __syncthreads();
    float acc = b2[lane];
#pragma unroll 8
    for (int i = 0; i < 64; ++i)
        acc = fmaf(xin[w][i], W2[i * 64 + lane], acc);
    tmp[w][lane] = tanhf(acc);
    __syncthreads();
    if (lane < 50) {
        float a = b3[lane];
#pragma unroll 8
        for (int j = 0; j < 64; ++j)
            a = fmaf(tmp[w][j], W3[j * 50 + lane], a);
        out[(size_t)row * 50 + lane] = a;
    }
}

// ---------------------------------------------------------------------------
extern "C" void kernel_launch(void* const* d_in, const int* in_sizes, int n_in,
                              void* d_out, int out_size, void* d_ws, size_t ws_size,
                              hipStream_t stream)
{
    const float* x    = (const float*)d_in[0];
    const int*   edge = (const int*)d_in[1];

    const float *g1_Wl = (const float*)d_in[2],  *g1_bl = (const float*)d_in[3];
    const float *g1_Wr = (const float*)d_in[4],  *g1_br = (const float*)d_in[5];
    const float *g1_att= (const float*)d_in[6],  *g1_b  = (const float*)d_in[7];
    const float *g2_Wl = (const float*)d_in[8],  *g2_bl = (const float*)d_in[9];
    const float *g2_Wr = (const float*)d_in[10], *g2_br = (const float*)d_in[11];
    const float *g2_att= (const float*)d_in[12], *g2_b  = (const float*)d_in[13];
    const float *r1_Wl = (const float*)d_in[14], *r1_bl = (const float*)d_in[15];
    const float *r1_Wr = (const float*)d_in[16], *r1_br = (const float*)d_in[17];
    const float *r1_att= (const float*)d_in[18], *r1_b  = (const float*)d_in[19];
    const float *f1_Wl = (const float*)d_in[20], *f1_bl = (const float*)d_in[21];
    const float *f1_Wr = (const float*)d_in[22], *f1_br = (const float*)d_in[23];
    const float *f1_att= (const float*)d_in[24], *f1_b  = (const float*)d_in[25];
    const float *gru0_Wih = (const float*)d_in[26], *gru0_Whh = (const float*)d_in[27];
    const float *gru0_bih = (const float*)d_in[28], *gru0_bhh = (const float*)d_in[29];
    const float *gru1_Wih = (const float*)d_in[30], *gru1_Whh = (const float*)d_in[31];
    const float *gru1_bih = (const float*)d_in[32], *gru1_bhh = (const float*)d_in[33];
    const float *rec2_W = (const float*)d_in[34], *rec2_b = (const float*)d_in[35];
    const float *rec3_W = (const float*)d_in[36], *rec3_b = (const float*)d_in[37];
    const float *fore3_W= (const float*)d_in[38], *fore3_b= (const float*)d_in[39];

    // workspace layout
    char* ws = (char*)d_ws;
    int*   srcs = (int*)ws;                              // 32*16*1024 ints (2 MB)
    float* buf1 = (float*)(ws + (4u << 20));             // [32768,128] 16 MB
    float* buf2 = buf1 + (size_t)32768 * 128;            // [32768,128] 16 MB
    float* buf3 = buf2 + (size_t)32768 * 128;            // [32768,64]   8 MB
    float* buf4 = buf3 + (size_t)32768 * 64;             // [32768,32]   4 MB

    float* recon = (float*)d_out;                        // [31,1024,50]
    float* fore  = recon + (size_t)31 * 1024 * 50;       // [31,1024,50]
    float* E     = fore  + (size_t)31 * 1024 * 50;       // [32,1024,32]

    // 1. adjacency -> source lists (parallel scan, order-free slots)
    k_srcs<<<Tt * (Nn / 64), 1024, 0, stream>>>(edge, srcs);

    // 2. GAT g1 (64 -> 64, H*C = 128)
    k_lin2t<64, 128><<<1024, 256, 0, stream>>>(x, g1_Wl, g1_bl, g1_Wr, g1_br, buf1, buf2, 32768);
    k_gat<64><<<8192, 256, 0, stream>>>(buf1, buf2, srcs, g1_att, g1_b, buf3, 32768);

    // 3. GAT g2 (64 -> 32, H*C = 64)
    k_lin2t<64, 64><<<512, 256, 0, stream>>>(buf3, g2_Wl, g2_bl, g2_Wr, g2_br, buf1, buf2, 32768);
    k_gat<32><<<8192, 256, 0, stream>>>(buf1, buf2, srcs, g2_att, g2_b, buf4, 32768);

    // 4. two stacked GRUs -> E (written straight into d_out)
    k_gru2<<<Nn / 8, 256, 0, stream>>>(buf4,
        gru0_Wih, gru0_Whh, gru0_bih, gru0_bhh,
        gru1_Wih, gru1_Whh, gru1_bih, gru1_bhh, E);

    // 5. reconstruct path: GAT r1 on E[1:], then tanh(@rec2)@rec3
    k_lin2t<32, 128><<<992, 256, 0, stream>>>(E + (size_t)Nn * 32, r1_Wl, r1_bl, r1_Wr, r1_br, buf1, buf2, 31744);
    k_gat<64><<<7936, 256, 0, stream>>>(buf1, buf2, srcs + KN * Nn, r1_att, r1_b, buf3, 31744);
    k_head<<<7936, 256, 0, stream>>>(buf3, rec2_W, rec2_b, rec3_W, rec3_b, recon, 31744);

    // 6. forecast path: GAT f1 on E[:-1], then tanh(@rec2)@fore3
    k_lin2t<32, 128><<<992, 256, 0, stream>>>(E, f1_Wl, f1_bl, f1_Wr, f1_br, buf1, buf2, 31744);
    k_gat<64><<<7936, 256, 0, stream>>>(buf1, buf2, srcs, f1_att, f1_b, buf3, 31744);
    k_head<<<7936, 256, 0, stream>>>(buf3, rec2_W, rec2_b, fore3_W, fore3_b, fore, 31744);

    (void)in_sizes; (void)n_in; (void)out_size; (void)ws_size;
}

// Round 4
// 485.954 us; speedup vs baseline: 2.3984x; 1.0987x over previous
//
#include <hip/hip_runtime.h>
#include <math.h>

static constexpr int Tt = 32;
static constexpr int Nn = 1024;
static constexpr int KN = 16;   // K + self

// ---------------------------------------------------------------------------
// 1. Recover source indices (order-free): for each (t,tgt) column, the 15
//    sources with edge[t,src,tgt]==1 land in slots 0..14 (any order — GAT is
//    permutation-invariant), slot 15 = self loop.
// ---------------------------------------------------------------------------
__global__ __launch_bounds__(1024) void k_srcs(const int* __restrict__ edge,
                                               int* __restrict__ srcs)
{
    __shared__ int cnt[64];
    const int t    = blockIdx.x >> 4;          // 0..31
    const int tgt0 = (blockIdx.x & 15) << 6;   // 0,64,...,960
    const int x = threadIdx.x & 63;            // target lane
    const int y = threadIdx.x >> 6;            // s-group 0..15
    if (threadIdx.x < 64) cnt[threadIdx.x] = 0;
    __syncthreads();

    const int tgt = tgt0 + x;
    const int* e = edge + (size_t)t * Nn * Nn + tgt;
    const int s0 = y * 64;

    for (int i0 = 0; i0 < 64; i0 += 16) {
        int v[16];
#pragma unroll
        for (int j = 0; j < 16; ++j)
            v[j] = e[(size_t)(s0 + i0 + j) * Nn];
#pragma unroll
        for (int j = 0; j < 16; ++j) {
            if (v[j] != 0) {
                int slot = atomicAdd(&cnt[x], 1);
                if (slot < KN - 1)
                    srcs[(t * KN + slot) * Nn + tgt] = s0 + i0 + j;
            }
        }
    }
    if (y == 0) srcs[(t * KN + (KN - 1)) * Nn + tgt] = tgt;
}

// ---------------------------------------------------------------------------
// 2. Register-blocked dual linear: Yl = X@Wl + bl, Yr = X@Wr + br.
// ---------------------------------------------------------------------------
template <int FI, int FO>
__global__ __launch_bounds__(256) void k_lin2t(
    const float* __restrict__ X,
    const float* __restrict__ Wl, const float* __restrict__ bl,
    const float* __restrict__ Wr, const float* __restrict__ br,
    float* __restrict__ Yl, float* __restrict__ Yr, int rows)
{
    constexpr int HC = FO / 2;          // thread's cols: c and c+HC
    constexpr int RG = 256 / HC;        // row-groups per block
    constexpr int R  = 8;               // rows per thread
    constexpr int BR = RG * R;          // rows per block
    constexpr int F4 = FI / 4;
    __shared__ float xs[BR][FI];

    const int tid  = threadIdx.x;
    const int c    = tid % HC;
    const int g    = tid / HC;
    const int row0 = blockIdx.x * BR;

#pragma unroll
    for (int idx = tid; idx < BR * F4; idx += 256) {
        int r = idx / F4, q = idx % F4;
        reinterpret_cast<float4*>(&xs[r][0])[q] =
            reinterpret_cast<const float4*>(X + (size_t)(row0 + r) * FI)[q];
    }
    __syncthreads();

    float al0[R], al1[R], ar0[R], ar1[R];
    const float bl0 = bl[c], bl1 = bl[c + HC], br0 = br[c], br1 = br[c + HC];
#pragma unroll
    for (int r = 0; r < R; ++r) { al0[r] = bl0; al1[r] = bl1; ar0[r] = br0; ar1[r] = br1; }

    const int rb = g * R;
#pragma unroll
    for (int i0 = 0; i0 < FI; i0 += 4) {
        float4 xv[R];
#pragma unroll
        for (int r = 0; r < R; ++r)
            xv[r] = *reinterpret_cast<const float4*>(&xs[rb + r][i0]);
#pragma unroll
        for (int j = 0; j < 4; ++j) {
            const float wl0 = Wl[(i0 + j) * FO + c];
            const float wl1 = Wl[(i0 + j) * FO + c + HC];
            const float wr0 = Wr[(i0 + j) * FO + c];
            const float wr1 = Wr[(i0 + j) * FO + c + HC];
#pragma unroll
            for (int r = 0; r < R; ++r) {
                const float xx = (&xv[r].x)[j];
                al0[r] = fmaf(xx, wl0, al0[r]);
                al1[r] = fmaf(xx, wl1, al1[r]);
                ar0[r] = fmaf(xx, wr0, ar0[r]);
                ar1[r] = fmaf(xx, wr1, ar1[r]);
            }
        }
    }
#pragma unroll
    for (int r = 0; r < R; ++r) {
        const size_t ro = (size_t)(row0 + rb + r) * FO;
        Yl[ro + c]      = al0[r];
        Yl[ro + c + HC] = al1[r];
        Yr[ro + c]      = ar0[r];
        Yr[ro + c + HC] = ar1[r];
    }
}

// ---------------------------------------------------------------------------
// 2b. Single linear to 96 cols (GRU input gates): Y = X@W^T + b.
//     W is PyTorch [96,32] row-major: Y[r,c] = b[c] + sum_i X[r,i]*W[c*32+i].
//     blockDim (96,2); 16 rows per block; W staged transposed+padded in LDS.
// ---------------------------------------------------------------------------
__global__ __launch_bounds__(192) void k_lin96(
    const float* __restrict__ X, const float* __restrict__ W,
    const float* __restrict__ b, float* __restrict__ Y)
{
    __shared__ float wT[32 * 97];       // wT[i*97+c] = W[c*32+i]
    __shared__ float xs[16][32];

    const int tid = threadIdx.y * 96 + threadIdx.x;
    const int row0 = blockIdx.x * 16;

    for (int idx = tid; idx < 3072; idx += 192) {
        int c = idx >> 5, i = idx & 31;
        wT[i * 97 + c] = W[idx];
    }
    for (int idx = tid; idx < 128; idx += 192)
        reinterpret_cast<float4*>(xs)[idx] =
            reinterpret_cast<const float4*>(X + (size_t)row0 * 32)[idx];
    __syncthreads();

    const int c  = threadIdx.x;
    const int rb = threadIdx.y * 8;
    float acc[8];
    const float bc = b[c];
#pragma unroll
    for (int r = 0; r < 8; ++r) acc[r] = bc;

#pragma unroll
    for (int i = 0; i < 32; ++i) {
        const float w = wT[i * 97 + c];
#pragma unroll
        for (int r = 0; r < 8; ++r)
            acc[r] = fmaf(xs[rb + r][i], w, acc[r]);
    }
#pragma unroll
    for (int r = 0; r < 8; ++r)
        Y[(size_t)(row0 + rb + r) * 96 + c] = acc[r];
}

// ---------------------------------------------------------------------------
// 2c. Serial GRU layer, input gates precomputed. One wave per 2 nodes.
//     Whh rows held in REGISTERS (statically indexed); h broadcast via
//     __shfl(width=32). No LDS, no barriers.
//     gi: [T*N, 96] (= x@Wih^T + bih); E: [T*N, 32].
// ---------------------------------------------------------------------------
__global__ __launch_bounds__(64) void k_gru1(
    const float* __restrict__ gi, const float* __restrict__ Whh,
    const float* __restrict__ bhh, float* __restrict__ E)
{
    const int d    = threadIdx.x & 31;
    const int node = blockIdx.x * 2 + (threadIdx.x >> 5);

    float wr_[32], wz_[32], wn_[32];
#pragma unroll
    for (int q = 0; q < 8; ++q) {
        *reinterpret_cast<float4*>(&wr_[q * 4]) =
            reinterpret_cast<const float4*>(Whh + (size_t)d * 32)[q];
        *reinterpret_cast<float4*>(&wz_[q * 4]) =
            reinterpret_cast<const float4*>(Whh + (size_t)(32 + d) * 32)[q];
        *reinterpret_cast<float4*>(&wn_[q * 4]) =
            reinterpret_cast<const float4*>(Whh + (size_t)(64 + d) * 32)[q];
    }
    const float br_ = bhh[d], bz_ = bhh[32 + d], bn_ = bhh[64 + d];

    float h = 0.0f;
    for (int t = 0; t < Tt; ++t) {
        const size_t base = ((size_t)t * Nn + node) * 96 + d;
        const float gr = gi[base], gz = gi[base + 32], gn = gi[base + 64];
        float ar = br_, az = bz_, an = bn_;
#pragma unroll
        for (int i = 0; i < 32; ++i) {
            const float hv = __shfl(h, i, 32);
            ar = fmaf(wr_[i], hv, ar);
            az = fmaf(wz_[i], hv, az);
            an = fmaf(wn_[i], hv, an);
        }
        const float r = 1.0f / (1.0f + expf(-(gr + ar)));
        const float z = 1.0f / (1.0f + expf(-(gz + az)));
        const float nn2 = tanhf(gn + r * an);
        h = (1.0f - z) * nn2 + z * h;
        E[((size_t)t * Nn + node) * 32 + d] = h;
    }
}

// ---------------------------------------------------------------------------
// 3. GATv2 attention + aggregate + mean-heads + bias + ELU.
// ---------------------------------------------------------------------------
template <int C>
__global__ __launch_bounds__(256) void k_gat(
    const float* __restrict__ gl, const float* __restrict__ gr,
    const int* __restrict__ srcs, const float* __restrict__ att,
    const float* __restrict__ bias, float* __restrict__ out, int rows)
{
    constexpr int HC = 2 * C;
    __shared__ float lds[4][KN][HC];
    const int lane = threadIdx.x & 63;
    const int w = threadIdx.x >> 6;
    const int wave = blockIdx.x * 4 + w;
    if (wave >= rows) return;
    const int t = wave >> 10;
    const int n = wave & (Nn - 1);

    float lo0[KN], lo1[KN];

    if (C == 64) {
        const float grl0 = gr[(size_t)wave * HC + lane];
        const float grl1 = gr[(size_t)wave * HC + 64 + lane];
        const float a0 = att[lane], a1 = att[64 + lane];
#pragma unroll
        for (int k = 0; k < KN; ++k) {
            int s = srcs[(t * KN + k) * Nn + n];
            const float* gsr = gl + ((size_t)t * Nn + s) * HC;
            float g0 = gsr[lane], g1 = gsr[64 + lane];
            lds[w][k][lane] = g0;
            lds[w][k][64 + lane] = g1;
            float e0 = g0 + grl0; e0 = e0 > 0.0f ? e0 : 0.2f * e0;
            float e1 = g1 + grl1; e1 = e1 > 0.0f ? e1 : 0.2f * e1;
            float p0 = e0 * a0, p1 = e1 * a1;
#pragma unroll
            for (int m = 1; m < 64; m <<= 1) {
                p0 += __shfl_xor(p0, m);
                p1 += __shfl_xor(p1, m);
            }
            lo0[k] = p0; lo1[k] = p1;
        }
    } else {
        const float grl = gr[(size_t)wave * HC + lane];
        const float a = att[lane];
#pragma unroll
        for (int k = 0; k < KN; ++k) {
            int s = srcs[(t * KN + k) * Nn + n];
            const float* gsr = gl + ((size_t)t * Nn + s) * HC;
            float g = gsr[lane];
            lds[w][k][lane] = g;
            float e = g + grl; e = e > 0.0f ? e : 0.2f * e;
            float p = e * a;
#pragma unroll
            for (int m = 1; m < 32; m <<= 1) p += __shfl_xor(p, m);
            float o = __shfl_xor(p, 32);
            lo0[k] = (lane < 32) ? p : o;
            lo1[k] = (lane < 32) ? o : p;
        }
    }

    __syncthreads();

    float m0 = lo0[0], m1 = lo1[0];
#pragma unroll
    for (int k = 1; k < KN; ++k) { m0 = fmaxf(m0, lo0[k]); m1 = fmaxf(m1, lo1[k]); }
    float s0 = 0.0f, s1 = 0.0f;
#pragma unroll
    for (int k = 0; k < KN; ++k) {
        lo0[k] = expf(lo0[k] - m0); s0 += lo0[k];
        lo1[k] = expf(lo1[k] - m1); s1 += lo1[k];
    }
    const float inv0 = 1.0f / s0, inv1 = 1.0f / s1;

    if (C == 64) {
        float acc0 = 0.0f, acc1 = 0.0f;
#pragma unroll
        for (int k = 0; k < KN; ++k) {
            acc0 = fmaf(lo0[k] * inv0, lds[w][k][lane], acc0);
            acc1 = fmaf(lo1[k] * inv1, lds[w][k][64 + lane], acc1);
        }
        float res = 0.5f * (acc0 + acc1) + bias[lane];
        res = res > 0.0f ? res : expm1f(res);
        out[(size_t)wave * C + lane] = res;
    } else {
        float acc = 0.0f;
#pragma unroll
        for (int k = 0; k < KN; ++k) {
            float al = (lane < 32) ? lo0[k] * inv0 : lo1[k] * inv1;
            acc = fmaf(al, lds[w][k][lane], acc);
        }
        float o = __shfl_xor(acc, 32);
        if (lane < 32) {
            float res = 0.5f * (acc + o) + bias[lane];
            res = res > 0.0f ? res : expm1f(res);
            out[(size_t)wave * C + lane] = res;
        }
    }
}

// ---------------------------------------------------------------------------
// 5. out[row,:] = tanh(in[row,:] @ W2 + b2) @ W3 + b3   (64 -> 64 -> 50)
// ---------------------------------------------------------------------------
__global__ __launch_bounds__(256) void k_head(
    const float* __restrict__ in, const float* __restrict__ W2,
    const float* __restrict__ b2, const float* __restrict__ W3,
    const float* __restrict__ b3, float* __restrict__ out, int rows)
{
    __shared__ float xin[4][64], tmp[4][64];
    const int lane = threadIdx.x & 63;
    const int w = threadIdx.x >> 6;
    const int row = blockIdx.x * 4 + w;
    xin[w][lane] = in[(size_t)row * 64 + lane];
    __syncthreads();
    float acc = b2[lane];
#pragma unroll 8
    for (int i = 0; i < 64; ++i)
        acc = fmaf(xin[w][i], W2[i * 64 + lane], acc);
    tmp[w][lane] = tanhf(acc);
    __syncthreads();
    if (lane < 50) {
        float a = b3[lane];
#pragma unroll 8
        for (int j = 0; j < 64; ++j)
            a = fmaf(tmp[w][j], W3[j * 50 + lane], a);
        out[(size_t)row * 50 + lane] = a;
    }
}

// ---------------------------------------------------------------------------
extern "C" void kernel_launch(void* const* d_in, const int* in_sizes, int n_in,
                              void* d_out, int out_size, void* d_ws, size_t ws_size,
                              hipStream_t stream)
{
    const float* x    = (const float*)d_in[0];
    const int*   edge = (const int*)d_in[1];

    const float *g1_Wl = (const float*)d_in[2],  *g1_bl = (const float*)d_in[3];
    const float *g1_Wr = (const float*)d_in[4],  *g1_br = (const float*)d_in[5];
    const float *g1_att= (const float*)d_in[6],  *g1_b  = (const float*)d_in[7];
    const float *g2_Wl = (const float*)d_in[8],  *g2_bl = (const float*)d_in[9];
    const float *g2_Wr = (const float*)d_in[10], *g2_br = (const float*)d_in[11];
    const float *g2_att= (const float*)d_in[12], *g2_b  = (const float*)d_in[13];
    const float *r1_Wl = (const float*)d_in[14], *r1_bl = (const float*)d_in[15];
    const float *r1_Wr = (const float*)d_in[16], *r1_br = (const float*)d_in[17];
    const float *r1_att= (const float*)d_in[18], *r1_b  = (const float*)d_in[19];
    const float *f1_Wl = (const float*)d_in[20], *f1_bl = (const float*)d_in[21];
    const float *f1_Wr = (const float*)d_in[22], *f1_br = (const float*)d_in[23];
    const float *f1_att= (const float*)d_in[24], *f1_b  = (const float*)d_in[25];
    const float *gru0_Wih = (const float*)d_in[26], *gru0_Whh = (const float*)d_in[27];
    const float *gru0_bih = (const float*)d_in[28], *gru0_bhh = (const float*)d_in[29];
    const float *gru1_Wih = (const float*)d_in[30], *gru1_Whh = (const float*)d_in[31];
    const float *gru1_bih = (const float*)d_in[32], *gru1_bhh = (const float*)d_in[33];
    const float *rec2_W = (const float*)d_in[34], *rec2_b = (const float*)d_in[35];
    const float *rec3_W = (const float*)d_in[36], *rec3_b = (const float*)d_in[37];
    const float *fore3_W= (const float*)d_in[38], *fore3_b= (const float*)d_in[39];

    // workspace layout
    char* ws = (char*)d_ws;
    int*   srcs = (int*)ws;                              // 32*16*1024 ints (2 MB)
    float* buf1 = (float*)(ws + (4u << 20));             // [32768,128] 16 MB
    float* buf2 = buf1 + (size_t)32768 * 128;            // [32768,128] 16 MB
    float* buf3 = buf2 + (size_t)32768 * 128;            // [32768,64]   8 MB
    float* buf4 = buf3 + (size_t)32768 * 64;             // [32768,32]   4 MB

    float* recon = (float*)d_out;                        // [31,1024,50]
    float* fore  = recon + (size_t)31 * 1024 * 50;       // [31,1024,50]
    float* E     = fore  + (size_t)31 * 1024 * 50;       // [32,1024,32]

    // 1. adjacency -> source lists (parallel scan, order-free slots)
    k_srcs<<<Tt * (Nn / 64), 1024, 0, stream>>>(edge, srcs);

    // 2. GAT g1 (64 -> 64, H*C = 128)
    k_lin2t<64, 128><<<1024, 256, 0, stream>>>(x, g1_Wl, g1_bl, g1_Wr, g1_br, buf1, buf2, 32768);
    k_gat<64><<<8192, 256, 0, stream>>>(buf1, buf2, srcs, g1_att, g1_b, buf3, 32768);

    // 3. GAT g2 (64 -> 32, H*C = 64)
    k_lin2t<64, 64><<<512, 256, 0, stream>>>(buf3, g2_Wl, g2_bl, g2_Wr, g2_br, buf1, buf2, 32768);
    k_gat<32><<<8192, 256, 0, stream>>>(buf1, buf2, srcs, g2_att, g2_b, buf4, 32768);

    // 4. two stacked GRUs -> E. Input-side gates hoisted to parallel GEMMs;
    //    serial kernels are register-weight, shuffle-broadcast, barrier-free.
    k_lin96<<<2048, dim3(96, 2), 0, stream>>>(buf4, gru0_Wih, gru0_bih, buf1);   // GI0
    k_gru1<<<512, 64, 0, stream>>>(buf1, gru0_Whh, gru0_bhh, buf3);              // E0
    k_lin96<<<2048, dim3(96, 2), 0, stream>>>(buf3, gru1_Wih, gru1_bih, buf2);   // GI1
    k_gru1<<<512, 64, 0, stream>>>(buf2, gru1_Whh, gru1_bhh, E);                 // E

    // 5. reconstruct path: GAT r1 on E[1:], then tanh(@rec2)@rec3
    k_lin2t<32, 128><<<992, 256, 0, stream>>>(E + (size_t)Nn * 32, r1_Wl, r1_bl, r1_Wr, r1_br, buf1, buf2, 31744);
    k_gat<64><<<7936, 256, 0, stream>>>(buf1, buf2, srcs + KN * Nn, r1_att, r1_b, buf3, 31744);
    k_head<<<7936, 256, 0, stream>>>(buf3, rec2_W, rec2_b, rec3_W, rec3_b, recon, 31744);

    // 6. forecast path: GAT f1 on E[:-1], then tanh(@rec2)@fore3
    k_lin2t<32, 128><<<992, 256, 0, stream>>>(E, f1_Wl, f1_bl, f1_Wr, f1_br, buf1, buf2, 31744);
    k_gat<64><<<7936, 256, 0, stream>>>(buf1, buf2, srcs, f1_att, f1_b, buf3, 31744);
    k_head<<<7936, 256, 0, stream>>>(buf3, rec2_W, rec2_b, fore3_W, fore3_b, fore, 31744);

    (void)in_sizes; (void)n_in; (void)out_size; (void)ws_size;
}

// Round 5
// 346.056 us; speedup vs baseline: 3.3680x; 1.4043x over previous
//
#include <hip/hip_runtime.h>
#include <math.h>

static constexpr int Tt = 32;
static constexpr int Nn = 1024;
static constexpr int KN = 16;   // K + self

// ---------------------------------------------------------------------------
// 1. Recover source indices (order-free): for each (t,tgt) column, the 15
//    sources with edge[t,src,tgt]==1 land in slots 0..14 (any order — GAT is
//    permutation-invariant), slot 15 = self loop.
// ---------------------------------------------------------------------------
__global__ __launch_bounds__(1024) void k_srcs(const int* __restrict__ edge,
                                               int* __restrict__ srcs)
{
    __shared__ int cnt[64];
    const int t    = blockIdx.x >> 4;          // 0..31
    const int tgt0 = (blockIdx.x & 15) << 6;   // 0,64,...,960
    const int x = threadIdx.x & 63;            // target lane
    const int y = threadIdx.x >> 6;            // s-group 0..15
    if (threadIdx.x < 64) cnt[threadIdx.x] = 0;
    __syncthreads();

    const int tgt = tgt0 + x;
    const int* e = edge + (size_t)t * Nn * Nn + tgt;
    const int s0 = y * 64;

    for (int i0 = 0; i0 < 64; i0 += 16) {
        int v[16];
#pragma unroll
        for (int j = 0; j < 16; ++j)
            v[j] = e[(size_t)(s0 + i0 + j) * Nn];
#pragma unroll
        for (int j = 0; j < 16; ++j) {
            if (v[j] != 0) {
                int slot = atomicAdd(&cnt[x], 1);
                if (slot < KN - 1)
                    srcs[(t * KN + slot) * Nn + tgt] = s0 + i0 + j;
            }
        }
    }
    if (y == 0) srcs[(t * KN + (KN - 1)) * Nn + tgt] = tgt;
}

// ---------------------------------------------------------------------------
// 2. Register-blocked dual linear: Yl = X@Wl + bl, Yr = X@Wr + br.
// ---------------------------------------------------------------------------
template <int FI, int FO>
__global__ __launch_bounds__(256) void k_lin2t(
    const float* __restrict__ X,
    const float* __restrict__ Wl, const float* __restrict__ bl,
    const float* __restrict__ Wr, const float* __restrict__ br,
    float* __restrict__ Yl, float* __restrict__ Yr, int rows)
{
    constexpr int HC = FO / 2;          // thread's cols: c and c+HC
    constexpr int RG = 256 / HC;        // row-groups per block
    constexpr int R  = 8;               // rows per thread
    constexpr int BR = RG * R;          // rows per block
    constexpr int F4 = FI / 4;
    __shared__ float xs[BR][FI];

    const int tid  = threadIdx.x;
    const int c    = tid % HC;
    const int g    = tid / HC;
    const int row0 = blockIdx.x * BR;

#pragma unroll
    for (int idx = tid; idx < BR * F4; idx += 256) {
        int r = idx / F4, q = idx % F4;
        reinterpret_cast<float4*>(&xs[r][0])[q] =
            reinterpret_cast<const float4*>(X + (size_t)(row0 + r) * FI)[q];
    }
    __syncthreads();

    float al0[R], al1[R], ar0[R], ar1[R];
    const float bl0 = bl[c], bl1 = bl[c + HC], br0 = br[c], br1 = br[c + HC];
#pragma unroll
    for (int r = 0; r < R; ++r) { al0[r] = bl0; al1[r] = bl1; ar0[r] = br0; ar1[r] = br1; }

    const int rb = g * R;
#pragma unroll
    for (int i0 = 0; i0 < FI; i0 += 4) {
        float4 xv[R];
#pragma unroll
        for (int r = 0; r < R; ++r)
            xv[r] = *reinterpret_cast<const float4*>(&xs[rb + r][i0]);
#pragma unroll
        for (int j = 0; j < 4; ++j) {
            const float wl0 = Wl[(i0 + j) * FO + c];
            const float wl1 = Wl[(i0 + j) * FO + c + HC];
            const float wr0 = Wr[(i0 + j) * FO + c];
            const float wr1 = Wr[(i0 + j) * FO + c + HC];
#pragma unroll
            for (int r = 0; r < R; ++r) {
                const float xx = (&xv[r].x)[j];
                al0[r] = fmaf(xx, wl0, al0[r]);
                al1[r] = fmaf(xx, wl1, al1[r]);
                ar0[r] = fmaf(xx, wr0, ar0[r]);
                ar1[r] = fmaf(xx, wr1, ar1[r]);
            }
        }
    }
#pragma unroll
    for (int r = 0; r < R; ++r) {
        const size_t ro = (size_t)(row0 + rb + r) * FO;
        Yl[ro + c]      = al0[r];
        Yl[ro + c + HC] = al1[r];
        Yr[ro + c]      = ar0[r];
        Yr[ro + c + HC] = ar1[r];
    }
}

// ---------------------------------------------------------------------------
// 2b. Single linear to 96 cols (GRU input gates): Y = X@W^T + b.
// ---------------------------------------------------------------------------
__global__ __launch_bounds__(192) void k_lin96(
    const float* __restrict__ X, const float* __restrict__ W,
    const float* __restrict__ b, float* __restrict__ Y)
{
    __shared__ float wT[32 * 97];       // wT[i*97+c] = W[c*32+i]
    __shared__ float xs[16][32];

    const int tid = threadIdx.y * 96 + threadIdx.x;
    const int row0 = blockIdx.x * 16;

    for (int idx = tid; idx < 3072; idx += 192) {
        int c = idx >> 5, i = idx & 31;
        wT[i * 97 + c] = W[idx];
    }
    for (int idx = tid; idx < 128; idx += 192)
        reinterpret_cast<float4*>(xs)[idx] =
            reinterpret_cast<const float4*>(X + (size_t)row0 * 32)[idx];
    __syncthreads();

    const int c  = threadIdx.x;
    const int rb = threadIdx.y * 8;
    float acc[8];
    const float bc = b[c];
#pragma unroll
    for (int r = 0; r < 8; ++r) acc[r] = bc;

#pragma unroll
    for (int i = 0; i < 32; ++i) {
        const float w = wT[i * 97 + c];
#pragma unroll
        for (int r = 0; r < 8; ++r)
            acc[r] = fmaf(xs[rb + r][i], w, acc[r]);
    }
#pragma unroll
    for (int r = 0; r < 8; ++r)
        Y[(size_t)(row0 + rb + r) * 96 + c] = acc[r];
}

// ---------------------------------------------------------------------------
// 2c. Serial GRU layer, input gates precomputed. One wave per 2 nodes.
// ---------------------------------------------------------------------------
__global__ __launch_bounds__(64) void k_gru1(
    const float* __restrict__ gi, const float* __restrict__ Whh,
    const float* __restrict__ bhh, float* __restrict__ E)
{
    const int d    = threadIdx.x & 31;
    const int node = blockIdx.x * 2 + (threadIdx.x >> 5);

    float wr_[32], wz_[32], wn_[32];
#pragma unroll
    for (int q = 0; q < 8; ++q) {
        *reinterpret_cast<float4*>(&wr_[q * 4]) =
            reinterpret_cast<const float4*>(Whh + (size_t)d * 32)[q];
        *reinterpret_cast<float4*>(&wz_[q * 4]) =
            reinterpret_cast<const float4*>(Whh + (size_t)(32 + d) * 32)[q];
        *reinterpret_cast<float4*>(&wn_[q * 4]) =
            reinterpret_cast<const float4*>(Whh + (size_t)(64 + d) * 32)[q];
    }
    const float br_ = bhh[d], bz_ = bhh[32 + d], bn_ = bhh[64 + d];

    float h = 0.0f;
    for (int t = 0; t < Tt; ++t) {
        const size_t base = ((size_t)t * Nn + node) * 96 + d;
        const float gr = gi[base], gz = gi[base + 32], gn = gi[base + 64];
        float ar = br_, az = bz_, an = bn_;
#pragma unroll
        for (int i = 0; i < 32; ++i) {
            const float hv = __shfl(h, i, 32);
            ar = fmaf(wr_[i], hv, ar);
            az = fmaf(wz_[i], hv, az);
            an = fmaf(wn_[i], hv, an);
        }
        const float r = 1.0f / (1.0f + expf(-(gr + ar)));
        const float z = 1.0f / (1.0f + expf(-(gz + az)));
        const float nn2 = tanhf(gn + r * an);
        h = (1.0f - z) * nn2 + z * h;
        E[((size_t)t * Nn + node) * 32 + d] = h;
    }
}

// ---------------------------------------------------------------------------
// 3. GATv2: LDS-free, register-resident, fold-reduced logits.
//    One wave per (t, target). Fold puts logit[k] at lanes (L>>s)&15;
//    softmax over k = 4 butterflies; alphas re-broadcast via __shfl.
//    Chunked XCD remap: contiguous logical blocks (same t-slice) -> one XCD.
// ---------------------------------------------------------------------------
#define FOLD(p, nv, m)                                            \
        _Pragma("unroll")                                         \
        for (int k2 = 0; k2 < (nv) / 2; ++k2) {                   \
            float a_ = p[k2], b_ = p[k2 + (nv) / 2];              \
            float t_ = (lane & (m)) ? a_ : b_;                    \
            float r_ = __shfl_xor(t_, (m));                       \
            p[k2] = ((lane & (m)) ? b_ : a_) + r_;                \
        }

template <int C>
__global__ __launch_bounds__(256) void k_gat(
    const float* __restrict__ gl, const float* __restrict__ gr,
    const int* __restrict__ srcs, const float* __restrict__ att,
    const float* __restrict__ bias, float* __restrict__ out, int rows)
{
    constexpr int HC = 2 * C;
    const int lane = threadIdx.x & 63;
    const int w = threadIdx.x >> 6;
    const int gridB = rows >> 2;               // exact (rows % 4 == 0)
    const int chunk = gridB >> 3;              // grids are multiples of 8
    const int bid = blockIdx.x;
    const int lb = (bid & 7) * chunk + (bid >> 3);
    const int wave = lb * 4 + w;
    const int t = wave >> 10;
    const int n = wave & (Nn - 1);

    if (C == 64) {
        const float grl0 = gr[(size_t)wave * HC + lane];
        const float grl1 = gr[(size_t)wave * HC + 64 + lane];
        const float a0 = att[lane], a1 = att[64 + lane];
        float g0[KN], g1[KN], p0[KN], p1[KN];
#pragma unroll
        for (int k = 0; k < KN; ++k) {
            int s = srcs[(t * KN + k) * Nn + n];
            const float* gsr = gl + ((size_t)t * Nn + s) * HC;
            g0[k] = gsr[lane]; g1[k] = gsr[64 + lane];
            float e0 = g0[k] + grl0; e0 = e0 > 0.0f ? e0 : 0.2f * e0;
            float e1 = g1[k] + grl1; e1 = e1 > 0.0f ? e1 : 0.2f * e1;
            p0[k] = e0 * a0; p1[k] = e1 * a1;
        }
        // fold: logit[k] lands at lanes with (L>>2)&15 == k
        FOLD(p0, 16, 32) FOLD(p0, 8, 16) FOLD(p0, 4, 8) FOLD(p0, 2, 4)
        p0[0] += __shfl_xor(p0[0], 2); p0[0] += __shfl_xor(p0[0], 1);
        FOLD(p1, 16, 32) FOLD(p1, 8, 16) FOLD(p1, 4, 8) FOLD(p1, 2, 4)
        p1[0] += __shfl_xor(p1[0], 2); p1[0] += __shfl_xor(p1[0], 1);
        const float lo0 = p0[0], lo1 = p1[0];

        float m0 = lo0, m1 = lo1;
#pragma unroll
        for (int m = 4; m <= 32; m <<= 1) {
            m0 = fmaxf(m0, __shfl_xor(m0, m));
            m1 = fmaxf(m1, __shfl_xor(m1, m));
        }
        const float e0 = expf(lo0 - m0), e1 = expf(lo1 - m1);
        float s0 = e0, s1 = e1;
#pragma unroll
        for (int m = 4; m <= 32; m <<= 1) {
            s0 += __shfl_xor(s0, m);
            s1 += __shfl_xor(s1, m);
        }
        const float A0 = e0 / s0, A1 = e1 / s1;

        float acc0 = 0.0f, acc1 = 0.0f;
#pragma unroll
        for (int k = 0; k < KN; ++k) {
            acc0 = fmaf(__shfl(A0, k * 4), g0[k], acc0);
            acc1 = fmaf(__shfl(A1, k * 4), g1[k], acc1);
        }
        float res = 0.5f * (acc0 + acc1) + bias[lane];
        res = res > 0.0f ? res : expm1f(res);
        out[(size_t)wave * C + lane] = res;
    } else {
        // C == 32: lane<32 = head0 channel lane, lane>=32 = head1 channel lane-32
        const float grl = gr[(size_t)wave * HC + lane];
        const float a = att[lane];
        float g[KN], p[KN];
#pragma unroll
        for (int k = 0; k < KN; ++k) {
            int s = srcs[(t * KN + k) * Nn + n];
            g[k] = gl[((size_t)t * Nn + s) * HC + lane];
            float e = g[k] + grl; e = e > 0.0f ? e : 0.2f * e;
            p[k] = e * a;
        }
        // fold within each 32-lane head half: logit[k] at (L>>1)&15
        FOLD(p, 16, 16) FOLD(p, 8, 8) FOLD(p, 4, 4) FOLD(p, 2, 2)
        p[0] += __shfl_xor(p[0], 1);
        const float lo = p[0];

        float mx = lo;
#pragma unroll
        for (int m = 2; m <= 16; m <<= 1) mx = fmaxf(mx, __shfl_xor(mx, m));
        const float e = expf(lo - mx);
        float s = e;
#pragma unroll
        for (int m = 2; m <= 16; m <<= 1) s += __shfl_xor(s, m);
        const float A = e / s;

        const int hb = lane & 32;
        float acc = 0.0f;
#pragma unroll
        for (int k = 0; k < KN; ++k)
            acc = fmaf(__shfl(A, hb + k * 2), g[k], acc);
        float o = __shfl_xor(acc, 32);
        if (lane < 32) {
            float res = 0.5f * (acc + o) + bias[lane];
            res = res > 0.0f ? res : expm1f(res);
            out[(size_t)wave * C + lane] = res;
        }
    }
}
#undef FOLD

// ---------------------------------------------------------------------------
// 5. out[row,:] = tanh(in[row,:] @ W2 + b2) @ W3 + b3   (64 -> 64 -> 50)
// ---------------------------------------------------------------------------
__global__ __launch_bounds__(256) void k_head(
    const float* __restrict__ in, const float* __restrict__ W2,
    const float* __restrict__ b2, const float* __restrict__ W3,
    const float* __restrict__ b3, float* __restrict__ out, int rows)
{
    __shared__ float xin[4][64], tmp[4][64];
    const int lane = threadIdx.x & 63;
    const int w = threadIdx.x >> 6;
    const int row = blockIdx.x * 4 + w;
    xin[w][lane] = in[(size_t)row * 64 + lane];
    __syncthreads();
    float acc = b2[lane];
#pragma unroll 8
    for (int i = 0; i < 64; ++i)
        acc = fmaf(xin[w][i], W2[i * 64 + lane], acc);
    tmp[w][lane] = tanhf(acc);
    __syncthreads();
    if (lane < 50) {
        float a = b3[lane];
#pragma unroll 8
        for (int j = 0; j < 64; ++j)
            a = fmaf(tmp[w][j], W3[j * 50 + lane], a);
        out[(size_t)row * 50 + lane] = a;
    }
}

// ---------------------------------------------------------------------------
extern "C" void kernel_launch(void* const* d_in, const int* in_sizes, int n_in,
                              void* d_out, int out_size, void* d_ws, size_t ws_size,
                              hipStream_t stream)
{
    const float* x    = (const float*)d_in[0];
    const int*   edge = (const int*)d_in[1];

    const float *g1_Wl = (const float*)d_in[2],  *g1_bl = (const float*)d_in[3];
    const float *g1_Wr = (const float*)d_in[4],  *g1_br = (const float*)d_in[5];
    const float *g1_att= (const float*)d_in[6],  *g1_b  = (const float*)d_in[7];
    const float *g2_Wl = (const float*)d_in[8],  *g2_bl = (const float*)d_in[9];
    const float *g2_Wr = (const float*)d_in[10], *g2_br = (const float*)d_in[11];
    const float *g2_att= (const float*)d_in[12], *g2_b  = (const float*)d_in[13];
    const float *r1_Wl = (const float*)d_in[14], *r1_bl = (const float*)d_in[15];
    const float *r1_Wr = (const float*)d_in[16], *r1_br = (const float*)d_in[17];
    const float *r1_att= (const float*)d_in[18], *r1_b  = (const float*)d_in[19];
    const float *f1_Wl = (const float*)d_in[20], *f1_bl = (const float*)d_in[21];
    const float *f1_Wr = (const float*)d_in[22], *f1_br = (const float*)d_in[23];
    const float *f1_att= (const float*)d_in[24], *f1_b  = (const float*)d_in[25];
    const float *gru0_Wih = (const float*)d_in[26], *gru0_Whh = (const float*)d_in[27];
    const float *gru0_bih = (const float*)d_in[28], *gru0_bhh = (const float*)d_in[29];
    const float *gru1_Wih = (const float*)d_in[30], *gru1_Whh = (const float*)d_in[31];
    const float *gru1_bih = (const float*)d_in[32], *gru1_bhh = (const float*)d_in[33];
    const float *rec2_W = (const float*)d_in[34], *rec2_b = (const float*)d_in[35];
    const float *rec3_W = (const float*)d_in[36], *rec3_b = (const float*)d_in[37];
    const float *fore3_W= (const float*)d_in[38], *fore3_b= (const float*)d_in[39];

    // workspace layout
    char* ws = (char*)d_ws;
    int*   srcs = (int*)ws;                              // 32*16*1024 ints (2 MB)
    float* buf1 = (float*)(ws + (4u << 20));             // [32768,128] 16 MB
    float* buf2 = buf1 + (size_t)32768 * 128;            // [32768,128] 16 MB
    float* buf3 = buf2 + (size_t)32768 * 128;            // [32768,64]   8 MB
    float* buf4 = buf3 + (size_t)32768 * 64;             // [32768,32]   4 MB

    float* recon = (float*)d_out;                        // [31,1024,50]
    float* fore  = recon + (size_t)31 * 1024 * 50;       // [31,1024,50]
    float* E     = fore  + (size_t)31 * 1024 * 50;       // [32,1024,32]

    // 1. adjacency -> source lists (parallel scan, order-free slots)
    k_srcs<<<Tt * (Nn / 64), 1024, 0, stream>>>(edge, srcs);

    // 2. GAT g1 (64 -> 64, H*C = 128)
    k_lin2t<64, 128><<<1024, 256, 0, stream>>>(x, g1_Wl, g1_bl, g1_Wr, g1_br, buf1, buf2, 32768);
    k_gat<64><<<8192, 256, 0, stream>>>(buf1, buf2, srcs, g1_att, g1_b, buf3, 32768);

    // 3. GAT g2 (64 -> 32, H*C = 64)
    k_lin2t<64, 64><<<512, 256, 0, stream>>>(buf3, g2_Wl, g2_bl, g2_Wr, g2_br, buf1, buf2, 32768);
    k_gat<32><<<8192, 256, 0, stream>>>(buf1, buf2, srcs, g2_att, g2_b, buf4, 32768);

    // 4. two stacked GRUs -> E. Input-side gates hoisted to parallel GEMMs;
    //    serial kernels are register-weight, shuffle-broadcast, barrier-free.
    k_lin96<<<2048, dim3(96, 2), 0, stream>>>(buf4, gru0_Wih, gru0_bih, buf1);   // GI0
    k_gru1<<<512, 64, 0, stream>>>(buf1, gru0_Whh, gru0_bhh, buf3);              // E0
    k_lin96<<<2048, dim3(96, 2), 0, stream>>>(buf3, gru1_Wih, gru1_bih, buf2);   // GI1
    k_gru1<<<512, 64, 0, stream>>>(buf2, gru1_Whh, gru1_bhh, E);                 // E

    // 5. reconstruct path: GAT r1 on E[1:], then tanh(@rec2)@rec3
    k_lin2t<32, 128><<<992, 256, 0, stream>>>(E + (size_t)Nn * 32, r1_Wl, r1_bl, r1_Wr, r1_br, buf1, buf2, 31744);
    k_gat<64><<<7936, 256, 0, stream>>>(buf1, buf2, srcs + KN * Nn, r1_att, r1_b, buf3, 31744);
    k_head<<<7936, 256, 0, stream>>>(buf3, rec2_W, rec2_b, rec3_W, rec3_b, recon, 31744);

    // 6. forecast path: GAT f1 on E[:-1], then tanh(@rec2)@fore3
    k_lin2t<32, 128><<<992, 256, 0, stream>>>(E, f1_Wl, f1_bl, f1_Wr, f1_br, buf1, buf2, 31744);
    k_gat<64><<<7936, 256, 0, stream>>>(buf1, buf2, srcs, f1_att, f1_b, buf3, 31744);
    k_head<<<7936, 256, 0, stream>>>(buf3, rec2_W, rec2_b, fore3_W, fore3_b, fore, 31744);

    (void)in_sizes; (void)n_in; (void)out_size; (void)ws_size;
}

// Round 6
// 338.321 us; speedup vs baseline: 3.4450x; 1.0229x over previous
//
#include <hip/hip_runtime.h>
#include <math.h>

static constexpr int Tt = 32;
static constexpr int Nn = 1024;
static constexpr int KN = 16;   // K + self

// ---------------------------------------------------------------------------
// 1. Recover source indices (order-free), TRANSPOSED layout srcs[t][n][16].
//    int4 scan: block = (64 x, 16 y), covers 256 targets; thread owns 4
//    targets (int4 over tgt), y-groups split the 1024 sources.
// ---------------------------------------------------------------------------
__global__ __launch_bounds__(1024) void k_srcs(const int* __restrict__ edge,
                                               int* __restrict__ srcs)
{
    __shared__ int cnt[256];
    const int t    = blockIdx.x >> 2;          // 0..31
    const int tgt0 = (blockIdx.x & 3) << 8;    // 0,256,512,768
    const int x = threadIdx.x & 63;            // int4 target group
    const int y = threadIdx.x >> 6;            // s-group 0..15
    if (threadIdx.x < 256) cnt[threadIdx.x] = 0;
    __syncthreads();

    const int c0 = 4 * x;                      // first of 4 targets
    const int s0 = y * 64;
    const int* e = edge + (size_t)t * Nn * Nn + tgt0 + c0;

#pragma unroll 4
    for (int s = s0; s < s0 + 64; ++s) {
        const int4 v = *reinterpret_cast<const int4*>(e + (size_t)s * Nn);
        if (v.x) { int sl = atomicAdd(&cnt[c0],     1); if (sl < KN - 1) srcs[((size_t)t * Nn + tgt0 + c0)     * KN + sl] = s; }
        if (v.y) { int sl = atomicAdd(&cnt[c0 + 1], 1); if (sl < KN - 1) srcs[((size_t)t * Nn + tgt0 + c0 + 1) * KN + sl] = s; }
        if (v.z) { int sl = atomicAdd(&cnt[c0 + 2], 1); if (sl < KN - 1) srcs[((size_t)t * Nn + tgt0 + c0 + 2) * KN + sl] = s; }
        if (v.w) { int sl = atomicAdd(&cnt[c0 + 3], 1); if (sl < KN - 1) srcs[((size_t)t * Nn + tgt0 + c0 + 3) * KN + sl] = s; }
    }
    if (threadIdx.x < 256)
        srcs[((size_t)t * Nn + tgt0 + threadIdx.x) * KN + (KN - 1)] = tgt0 + threadIdx.x;
}

// ---------------------------------------------------------------------------
// 2. Register-blocked dual linear, HEAD-INTERLEAVED output:
//    Y[row] holds float2 pairs P[c] = (col c, col c+HC)  (c in [0,HC)).
// ---------------------------------------------------------------------------
template <int FI, int FO>
__global__ __launch_bounds__(256) void k_lin2t(
    const float* __restrict__ X,
    const float* __restrict__ Wl, const float* __restrict__ bl,
    const float* __restrict__ Wr, const float* __restrict__ br,
    float* __restrict__ Yl, float* __restrict__ Yr, int rows)
{
    constexpr int HC = FO / 2;
    constexpr int RG = 256 / HC;
    constexpr int R  = 8;
    constexpr int BR = RG * R;
    constexpr int F4 = FI / 4;
    __shared__ float xs[BR][FI];

    const int tid  = threadIdx.x;
    const int c    = tid % HC;
    const int g    = tid / HC;
    const int row0 = blockIdx.x * BR;

#pragma unroll
    for (int idx = tid; idx < BR * F4; idx += 256) {
        int r = idx / F4, q = idx % F4;
        reinterpret_cast<float4*>(&xs[r][0])[q] =
            reinterpret_cast<const float4*>(X + (size_t)(row0 + r) * FI)[q];
    }
    __syncthreads();

    float al0[R], al1[R], ar0[R], ar1[R];
    const float bl0 = bl[c], bl1 = bl[c + HC], br0 = br[c], br1 = br[c + HC];
#pragma unroll
    for (int r = 0; r < R; ++r) { al0[r] = bl0; al1[r] = bl1; ar0[r] = br0; ar1[r] = br1; }

    const int rb = g * R;
#pragma unroll
    for (int i0 = 0; i0 < FI; i0 += 4) {
        float4 xv[R];
#pragma unroll
        for (int r = 0; r < R; ++r)
            xv[r] = *reinterpret_cast<const float4*>(&xs[rb + r][i0]);
#pragma unroll
        for (int j = 0; j < 4; ++j) {
            const float wl0 = Wl[(i0 + j) * FO + c];
            const float wl1 = Wl[(i0 + j) * FO + c + HC];
            const float wr0 = Wr[(i0 + j) * FO + c];
            const float wr1 = Wr[(i0 + j) * FO + c + HC];
#pragma unroll
            for (int r = 0; r < R; ++r) {
                const float xx = (&xv[r].x)[j];
                al0[r] = fmaf(xx, wl0, al0[r]);
                al1[r] = fmaf(xx, wl1, al1[r]);
                ar0[r] = fmaf(xx, wr0, ar0[r]);
                ar1[r] = fmaf(xx, wr1, ar1[r]);
            }
        }
    }
#pragma unroll
    for (int r = 0; r < R; ++r) {
        const size_t ro = (size_t)(row0 + rb + r) * FO;
        reinterpret_cast<float2*>(Yl + ro)[c] = make_float2(al0[r], al1[r]);
        reinterpret_cast<float2*>(Yr + ro)[c] = make_float2(ar0[r], ar1[r]);
    }
}

// ---------------------------------------------------------------------------
// 2b. Single linear to 96 cols (GRU input gates): Y = X@W^T + b.
// ---------------------------------------------------------------------------
__global__ __launch_bounds__(192) void k_lin96(
    const float* __restrict__ X, const float* __restrict__ W,
    const float* __restrict__ b, float* __restrict__ Y)
{
    __shared__ float wT[32 * 97];       // wT[i*97+c] = W[c*32+i]
    __shared__ float xs[16][32];

    const int tid = threadIdx.y * 96 + threadIdx.x;
    const int row0 = blockIdx.x * 16;

    for (int idx = tid; idx < 3072; idx += 192) {
        int c = idx >> 5, i = idx & 31;
        wT[i * 97 + c] = W[idx];
    }
    for (int idx = tid; idx < 128; idx += 192)
        reinterpret_cast<float4*>(xs)[idx] =
            reinterpret_cast<const float4*>(X + (size_t)row0 * 32)[idx];
    __syncthreads();

    const int c  = threadIdx.x;
    const int rb = threadIdx.y * 8;
    float acc[8];
    const float bc = b[c];
#pragma unroll
    for (int r = 0; r < 8; ++r) acc[r] = bc;

#pragma unroll
    for (int i = 0; i < 32; ++i) {
        const float w = wT[i * 97 + c];
#pragma unroll
        for (int r = 0; r < 8; ++r)
            acc[r] = fmaf(xs[rb + r][i], w, acc[r]);
    }
#pragma unroll
    for (int r = 0; r < 8; ++r)
        Y[(size_t)(row0 + rb + r) * 96 + c] = acc[r];
}

// ---------------------------------------------------------------------------
// 2c. Serial GRU layer, input gates precomputed. One wave per 2 nodes.
// ---------------------------------------------------------------------------
__global__ __launch_bounds__(64) void k_gru1(
    const float* __restrict__ gi, const float* __restrict__ Whh,
    const float* __restrict__ bhh, float* __restrict__ E)
{
    const int d    = threadIdx.x & 31;
    const int node = blockIdx.x * 2 + (threadIdx.x >> 5);

    float wr_[32], wz_[32], wn_[32];
#pragma unroll
    for (int q = 0; q < 8; ++q) {
        *reinterpret_cast<float4*>(&wr_[q * 4]) =
            reinterpret_cast<const float4*>(Whh + (size_t)d * 32)[q];
        *reinterpret_cast<float4*>(&wz_[q * 4]) =
            reinterpret_cast<const float4*>(Whh + (size_t)(32 + d) * 32)[q];
        *reinterpret_cast<float4*>(&wn_[q * 4]) =
            reinterpret_cast<const float4*>(Whh + (size_t)(64 + d) * 32)[q];
    }
    const float br_ = bhh[d], bz_ = bhh[32 + d], bn_ = bhh[64 + d];

    float h = 0.0f;
    for (int t = 0; t < Tt; ++t) {
        const size_t base = ((size_t)t * Nn + node) * 96 + d;
        const float gr = gi[base], gz = gi[base + 32], gn = gi[base + 64];
        float ar = br_, az = bz_, an = bn_;
#pragma unroll
        for (int i = 0; i < 32; ++i) {
            const float hv = __shfl(h, i, 32);
            ar = fmaf(wr_[i], hv, ar);
            az = fmaf(wz_[i], hv, az);
            an = fmaf(wn_[i], hv, an);
        }
        const float r = 1.0f / (1.0f + expf(-(gr + ar)));
        const float z = 1.0f / (1.0f + expf(-(gz + az)));
        const float nn2 = tanhf(gn + r * an);
        h = (1.0f - z) * nn2 + z * h;
        E[((size_t)t * Nn + node) * 32 + d] = h;
    }
}

// ---------------------------------------------------------------------------
// 3. GATv2 C=64, LDS-free fold-reduce; interleaved gl/gr (float2 per lane);
//    srcs[t][n][16] via int4 broadcasts. Optional fused MLP head
//    (tanh(res@W2+b2)@W3+b3, out stride 50).
// ---------------------------------------------------------------------------
#define FOLD(p, nv, m)                                            \
        _Pragma("unroll")                                         \
        for (int k2 = 0; k2 < (nv) / 2; ++k2) {                   \
            float a_ = p[k2], b_ = p[k2 + (nv) / 2];              \
            float t_ = (lane & (m)) ? a_ : b_;                    \
            float r_ = __shfl_xor(t_, (m));                       \
            p[k2] = ((lane & (m)) ? b_ : a_) + r_;                \
        }

template <bool HEAD>
__global__ __launch_bounds__(256) void k_gat64(
    const float* __restrict__ gl, const float* __restrict__ gr,
    const int* __restrict__ srcs, const float* __restrict__ att,
    const float* __restrict__ bias, float* __restrict__ out, int rows,
    const float* __restrict__ W2, const float* __restrict__ b2,
    const float* __restrict__ W3, const float* __restrict__ b3)
{
    __shared__ float hb[4][64];
    const int lane = threadIdx.x & 63;
    const int w = threadIdx.x >> 6;
    const int gridB = rows >> 2;
    const int chunk = gridB >> 3;
    const int bid = blockIdx.x;
    const int lb = (bid & 7) * chunk + (bid >> 3);
    const int wave = lb * 4 + w;
    const int t = wave >> 10;
    const int n = wave & (Nn - 1);

    const float2 grl = reinterpret_cast<const float2*>(gr + (size_t)wave * 128)[lane];
    const float a0 = att[lane], a1 = att[64 + lane];

    const int4* sp = reinterpret_cast<const int4*>(srcs + ((size_t)t * Nn + n) * KN);
    const int4 sA = sp[0], sB = sp[1], sC = sp[2], sD = sp[3];
    int s[KN] = {sA.x, sA.y, sA.z, sA.w, sB.x, sB.y, sB.z, sB.w,
                 sC.x, sC.y, sC.z, sC.w, sD.x, sD.y, sD.z, sD.w};

    float2 g[KN];
    float p0[KN], p1[KN];
#pragma unroll
    for (int k = 0; k < KN; ++k) {
        g[k] = reinterpret_cast<const float2*>(gl + ((size_t)t * Nn + s[k]) * 128)[lane];
        float e0 = g[k].x + grl.x; e0 = e0 > 0.0f ? e0 : 0.2f * e0;
        float e1 = g[k].y + grl.y; e1 = e1 > 0.0f ? e1 : 0.2f * e1;
        p0[k] = e0 * a0; p1[k] = e1 * a1;
    }
    FOLD(p0, 16, 32) FOLD(p0, 8, 16) FOLD(p0, 4, 8) FOLD(p0, 2, 4)
    p0[0] += __shfl_xor(p0[0], 2); p0[0] += __shfl_xor(p0[0], 1);
    FOLD(p1, 16, 32) FOLD(p1, 8, 16) FOLD(p1, 4, 8) FOLD(p1, 2, 4)
    p1[0] += __shfl_xor(p1[0], 2); p1[0] += __shfl_xor(p1[0], 1);
    const float lo0 = p0[0], lo1 = p1[0];

    float m0 = lo0, m1 = lo1;
#pragma unroll
    for (int m = 4; m <= 32; m <<= 1) {
        m0 = fmaxf(m0, __shfl_xor(m0, m));
        m1 = fmaxf(m1, __shfl_xor(m1, m));
    }
    const float e0 = expf(lo0 - m0), e1 = expf(lo1 - m1);
    float s0 = e0, s1 = e1;
#pragma unroll
    for (int m = 4; m <= 32; m <<= 1) {
        s0 += __shfl_xor(s0, m);
        s1 += __shfl_xor(s1, m);
    }
    const float A0 = e0 / s0, A1 = e1 / s1;

    float acc0 = 0.0f, acc1 = 0.0f;
#pragma unroll
    for (int k = 0; k < KN; ++k) {
        acc0 = fmaf(__shfl(A0, k * 4), g[k].x, acc0);
        acc1 = fmaf(__shfl(A1, k * 4), g[k].y, acc1);
    }
    float res = 0.5f * (acc0 + acc1) + bias[lane];
    res = res > 0.0f ? res : expm1f(res);

    if (!HEAD) {
        out[(size_t)wave * 64 + lane] = res;
    } else {
        // tanh(res @ W2 + b2) @ W3 + b3 -> out[wave][50]
        hb[w][lane] = res;
        __builtin_amdgcn_s_waitcnt(0);           // lgkm drain (same-wave LDS RAW)
        float acc = b2[lane];
#pragma unroll
        for (int i4 = 0; i4 < 16; ++i4) {
            const float4 hv = reinterpret_cast<const float4*>(&hb[w][0])[i4];
            acc = fmaf(hv.x, W2[(i4 * 4 + 0) * 64 + lane], acc);
            acc = fmaf(hv.y, W2[(i4 * 4 + 1) * 64 + lane], acc);
            acc = fmaf(hv.z, W2[(i4 * 4 + 2) * 64 + lane], acc);
            acc = fmaf(hv.w, W2[(i4 * 4 + 3) * 64 + lane], acc);
        }
        const float th = tanhf(acc);
        __builtin_amdgcn_s_waitcnt(0);
        hb[w][lane] = th;
        __builtin_amdgcn_s_waitcnt(0);
        if (lane < 50) {
            float a = b3[lane];
#pragma unroll
            for (int j4 = 0; j4 < 16; ++j4) {
                const float4 hv = reinterpret_cast<const float4*>(&hb[w][0])[j4];
                a = fmaf(hv.x, W3[(j4 * 4 + 0) * 50 + lane], a);
                a = fmaf(hv.y, W3[(j4 * 4 + 1) * 50 + lane], a);
                a = fmaf(hv.z, W3[(j4 * 4 + 2) * 50 + lane], a);
                a = fmaf(hv.w, W3[(j4 * 4 + 3) * 50 + lane], a);
            }
            out[(size_t)wave * 50 + lane] = a;
        }
    }
}

// ---------------------------------------------------------------------------
// 3b. GATv2 C=32: TWO targets per wave (lanes 0-31 / 32-63), both heads per
//     lane via interleaved float2. Fold within 32-lane halves.
// ---------------------------------------------------------------------------
__global__ __launch_bounds__(256) void k_gat32(
    const float* __restrict__ gl, const float* __restrict__ gr,
    const int* __restrict__ srcs, const float* __restrict__ att,
    const float* __restrict__ bias, float* __restrict__ out, int waves)
{
    const int lane = threadIdx.x & 63;
    const int w = threadIdx.x >> 6;
    const int gridB = waves >> 2;
    const int chunk = gridB >> 3;
    const int bid = blockIdx.x;
    const int lb = (bid & 7) * chunk + (bid >> 3);
    const int wv = lb * 4 + w;
    const int tgt = 2 * wv + (lane >> 5);      // this lane's target
    const int t = tgt >> 10;
    const int n = tgt & (Nn - 1);
    const int c = lane & 31;

    const float2 grl = reinterpret_cast<const float2*>(gr + (size_t)tgt * 64)[c];
    const float a0 = att[c], a1 = att[32 + c];

    const int4* sp = reinterpret_cast<const int4*>(srcs + ((size_t)t * Nn + n) * KN);
    const int4 sA = sp[0], sB = sp[1], sC = sp[2], sD = sp[3];
    int s[KN] = {sA.x, sA.y, sA.z, sA.w, sB.x, sB.y, sB.z, sB.w,
                 sC.x, sC.y, sC.z, sC.w, sD.x, sD.y, sD.z, sD.w};

    float2 g[KN];
    float p0[KN], p1[KN];
#pragma unroll
    for (int k = 0; k < KN; ++k) {
        g[k] = reinterpret_cast<const float2*>(gl + ((size_t)t * Nn + s[k]) * 64)[c];
        float e0 = g[k].x + grl.x; e0 = e0 > 0.0f ? e0 : 0.2f * e0;
        float e1 = g[k].y + grl.y; e1 = e1 > 0.0f ? e1 : 0.2f * e1;
        p0[k] = e0 * a0; p1[k] = e1 * a1;
    }
    // fold within 32-lane halves: logit[k] at (lane&31)>>1 == k
    FOLD(p0, 16, 16) FOLD(p0, 8, 8) FOLD(p0, 4, 4) FOLD(p0, 2, 2)
    p0[0] += __shfl_xor(p0[0], 1);
    FOLD(p1, 16, 16) FOLD(p1, 8, 8) FOLD(p1, 4, 4) FOLD(p1, 2, 2)
    p1[0] += __shfl_xor(p1[0], 1);
    const float lo0 = p0[0], lo1 = p1[0];

    float m0 = lo0, m1 = lo1;
#pragma unroll
    for (int m = 2; m <= 16; m <<= 1) {
        m0 = fmaxf(m0, __shfl_xor(m0, m));
        m1 = fmaxf(m1, __shfl_xor(m1, m));
    }
    const float e0 = expf(lo0 - m0), e1 = expf(lo1 - m1);
    float s0 = e0, s1 = e1;
#pragma unroll
    for (int m = 2; m <= 16; m <<= 1) {
        s0 += __shfl_xor(s0, m);
        s1 += __shfl_xor(s1, m);
    }
    const float A0 = e0 / s0, A1 = e1 / s1;

    const int half = lane & 32;
    float acc0 = 0.0f, acc1 = 0.0f;
#pragma unroll
    for (int k = 0; k < KN; ++k) {
        acc0 = fmaf(__shfl(A0, half + k * 2), g[k].x, acc0);
        acc1 = fmaf(__shfl(A1, half + k * 2), g[k].y, acc1);
    }
    float res = 0.5f * (acc0 + acc1) + bias[c];
    res = res > 0.0f ? res : expm1f(res);
    out[(size_t)tgt * 32 + c] = res;
}
#undef FOLD

// ---------------------------------------------------------------------------
extern "C" void kernel_launch(void* const* d_in, const int* in_sizes, int n_in,
                              void* d_out, int out_size, void* d_ws, size_t ws_size,
                              hipStream_t stream)
{
    const float* x    = (const float*)d_in[0];
    const int*   edge = (const int*)d_in[1];

    const float *g1_Wl = (const float*)d_in[2],  *g1_bl = (const float*)d_in[3];
    const float *g1_Wr = (const float*)d_in[4],  *g1_br = (const float*)d_in[5];
    const float *g1_att= (const float*)d_in[6],  *g1_b  = (const float*)d_in[7];
    const float *g2_Wl = (const float*)d_in[8],  *g2_bl = (const float*)d_in[9];
    const float *g2_Wr = (const float*)d_in[10], *g2_br = (const float*)d_in[11];
    const float *g2_att= (const float*)d_in[12], *g2_b  = (const float*)d_in[13];
    const float *r1_Wl = (const float*)d_in[14], *r1_bl = (const float*)d_in[15];
    const float *r1_Wr = (const float*)d_in[16], *r1_br = (const float*)d_in[17];
    const float *r1_att= (const float*)d_in[18], *r1_b  = (const float*)d_in[19];
    const float *f1_Wl = (const float*)d_in[20], *f1_bl = (const float*)d_in[21];
    const float *f1_Wr = (const float*)d_in[22], *f1_br = (const float*)d_in[23];
    const float *f1_att= (const float*)d_in[24], *f1_b  = (const float*)d_in[25];
    const float *gru0_Wih = (const float*)d_in[26], *gru0_Whh = (const float*)d_in[27];
    const float *gru0_bih = (const float*)d_in[28], *gru0_bhh = (const float*)d_in[29];
    const float *gru1_Wih = (const float*)d_in[30], *gru1_Whh = (const float*)d_in[31];
    const float *gru1_bih = (const float*)d_in[32], *gru1_bhh = (const float*)d_in[33];
    const float *rec2_W = (const float*)d_in[34], *rec2_b = (const float*)d_in[35];
    const float *rec3_W = (const float*)d_in[36], *rec3_b = (const float*)d_in[37];
    const float *fore3_W= (const float*)d_in[38], *fore3_b= (const float*)d_in[39];

    // workspace layout
    char* ws = (char*)d_ws;
    int*   srcs = (int*)ws;                              // [32][1024][16] ints (2 MB)
    float* buf1 = (float*)(ws + (4u << 20));             // [32768,128] 16 MB
    float* buf2 = buf1 + (size_t)32768 * 128;            // [32768,128] 16 MB
    float* buf3 = buf2 + (size_t)32768 * 128;            // [32768,64]   8 MB
    float* buf4 = buf3 + (size_t)32768 * 64;             // [32768,32]   4 MB

    float* recon = (float*)d_out;                        // [31,1024,50]
    float* fore  = recon + (size_t)31 * 1024 * 50;       // [31,1024,50]
    float* E     = fore  + (size_t)31 * 1024 * 50;       // [32,1024,32]

    // 1. adjacency -> source lists (int4 scan, transposed layout)
    k_srcs<<<Tt * 4, 1024, 0, stream>>>(edge, srcs);

    // 2. GAT g1 (64 -> 64): interleaved projections, fold-GAT
    k_lin2t<64, 128><<<1024, 256, 0, stream>>>(x, g1_Wl, g1_bl, g1_Wr, g1_br, buf1, buf2, 32768);
    k_gat64<false><<<8192, 256, 0, stream>>>(buf1, buf2, srcs, g1_att, g1_b, buf3, 32768,
                                             nullptr, nullptr, nullptr, nullptr);

    // 3. GAT g2 (64 -> 32): 2 targets/wave
    k_lin2t<64, 64><<<512, 256, 0, stream>>>(buf3, g2_Wl, g2_bl, g2_Wr, g2_br, buf1, buf2, 32768);
    k_gat32<<<4096, 256, 0, stream>>>(buf1, buf2, srcs, g2_att, g2_b, buf4, 16384);

    // 4. two stacked GRUs -> E
    k_lin96<<<2048, dim3(96, 2), 0, stream>>>(buf4, gru0_Wih, gru0_bih, buf1);   // GI0
    k_gru1<<<512, 64, 0, stream>>>(buf1, gru0_Whh, gru0_bhh, buf3);              // E0
    k_lin96<<<2048, dim3(96, 2), 0, stream>>>(buf3, gru1_Wih, gru1_bih, buf2);   // GI1
    k_gru1<<<512, 64, 0, stream>>>(buf2, gru1_Whh, gru1_bhh, E);                 // E

    // 5. reconstruct: GAT r1 on E[1:] + fused tanh(@rec2)@rec3 head
    k_lin2t<32, 128><<<992, 256, 0, stream>>>(E + (size_t)Nn * 32, r1_Wl, r1_bl, r1_Wr, r1_br, buf1, buf2, 31744);
    k_gat64<true><<<7936, 256, 0, stream>>>(buf1, buf2, srcs + (size_t)KN * Nn, r1_att, r1_b, recon, 31744,
                                            rec2_W, rec2_b, rec3_W, rec3_b);

    // 6. forecast: GAT f1 on E[:-1] + fused tanh(@rec2)@fore3 head
    k_lin2t<32, 128><<<992, 256, 0, stream>>>(E, f1_Wl, f1_bl, f1_Wr, f1_br, buf1, buf2, 31744);
    k_gat64<true><<<7936, 256, 0, stream>>>(buf1, buf2, srcs, f1_att, f1_b, fore, 31744,
                                            rec2_W, rec2_b, fore3_W, fore3_b);

    (void)in_sizes; (void)n_in; (void)out_size; (void)ws_size;
}

// Round 7
// 317.584 us; speedup vs baseline: 3.6699x; 1.0653x over previous
//
#include <hip/hip_runtime.h>
#include <math.h>

static constexpr int Tt = 32;
static constexpr int Nn = 1024;
static constexpr int KN = 16;   // K + self

// ---------------------------------------------------------------------------
// Cross-lane primitives: DPP for xor1/xor2 (pure VALU), ds_swizzle otherwise.
// ---------------------------------------------------------------------------
template <int M>
__device__ __forceinline__ float lane_xor(float v) {
    if constexpr (M == 1)
        return __int_as_float(__builtin_amdgcn_mov_dpp(__float_as_int(v), 0xB1, 0xF, 0xF, true));
    else if constexpr (M == 2)
        return __int_as_float(__builtin_amdgcn_mov_dpp(__float_as_int(v), 0x4E, 0xF, 0xF, true));
    else
        return __shfl_xor(v, M);
}

__device__ __forceinline__ float bcastlane(float v, int l) {
    return __int_as_float(__builtin_amdgcn_readlane(__float_as_int(v), l));
}

__device__ __forceinline__ constexpr int rev4(int k) {
    return ((k & 1) << 3) | ((k & 2) << 1) | ((k & 4) >> 1) | ((k & 8) >> 3);
}

// fold NV values into NV/2, routing by lane bit M (value MSB <-> lane bit M)
template <int NV, int M>
__device__ __forceinline__ void fstage(float* p, int lane) {
#pragma unroll
    for (int k2 = 0; k2 < NV / 2; ++k2) {
        float a_ = p[k2], b_ = p[k2 + NV / 2];
        float t_ = (lane & M) ? a_ : b_;
        float r_ = lane_xor<M>(t_);
        p[k2] = ((lane & M) ? b_ : a_) + r_;
    }
}
// 16 values -> logit[k] at lanes with (lane&15) == rev4(k); partial over 16 lanes
__device__ __forceinline__ float fold16(float* p, int lane) {
    fstage<16, 1>(p, lane);
    fstage<8, 2>(p, lane);
    fstage<4, 4>(p, lane);
    fstage<2, 8>(p, lane);
    return p[0];
}
// reductions over lane bits 0..3 (the k-index bits after fold16)
__device__ __forceinline__ float rmax16(float x) {
    x = fmaxf(x, lane_xor<1>(x)); x = fmaxf(x, lane_xor<2>(x));
    x = fmaxf(x, lane_xor<4>(x)); x = fmaxf(x, lane_xor<8>(x));
    return x;
}
__device__ __forceinline__ float rsum16(float x) {
    x += lane_xor<1>(x); x += lane_xor<2>(x);
    x += lane_xor<4>(x); x += lane_xor<8>(x);
    return x;
}

// ---------------------------------------------------------------------------
// 1. Recover source indices (order-free), layout srcs[t][n][16].
//    256 blocks (t x 8 stripes of 128 targets); 8-deep int4 pipeline.
// ---------------------------------------------------------------------------
__global__ __launch_bounds__(1024) void k_srcs(const int* __restrict__ edge,
                                               int* __restrict__ srcs)
{
    __shared__ int cnt[128];
    const int t    = blockIdx.x >> 3;          // 0..31
    const int tgt0 = (blockIdx.x & 7) << 7;    // 0,128,...,896
    const int x = threadIdx.x & 31;            // int4 target group (4 targets)
    const int y = threadIdx.x >> 5;            // s-group 0..31
    if (threadIdx.x < 128) cnt[threadIdx.x] = 0;
    __syncthreads();

    const int c0 = 4 * x;
    const int s0 = y * 32;
    const int* e = edge + (size_t)t * Nn * Nn + tgt0 + c0;

    for (int i0 = 0; i0 < 32; i0 += 8) {
        int4 v[8];
#pragma unroll
        for (int j = 0; j < 8; ++j)
            v[j] = *reinterpret_cast<const int4*>(e + (size_t)(s0 + i0 + j) * Nn);
#pragma unroll
        for (int j = 0; j < 8; ++j) {
            const int s = s0 + i0 + j;
            if (v[j].x) { int sl = atomicAdd(&cnt[c0],     1); if (sl < KN - 1) srcs[((size_t)t * Nn + tgt0 + c0)     * KN + sl] = s; }
            if (v[j].y) { int sl = atomicAdd(&cnt[c0 + 1], 1); if (sl < KN - 1) srcs[((size_t)t * Nn + tgt0 + c0 + 1) * KN + sl] = s; }
            if (v[j].z) { int sl = atomicAdd(&cnt[c0 + 2], 1); if (sl < KN - 1) srcs[((size_t)t * Nn + tgt0 + c0 + 2) * KN + sl] = s; }
            if (v[j].w) { int sl = atomicAdd(&cnt[c0 + 3], 1); if (sl < KN - 1) srcs[((size_t)t * Nn + tgt0 + c0 + 3) * KN + sl] = s; }
        }
    }
    if (threadIdx.x < 128)
        srcs[((size_t)t * Nn + tgt0 + threadIdx.x) * KN + (KN - 1)] = tgt0 + threadIdx.x;
}

// ---------------------------------------------------------------------------
// 2. Register-blocked dual linear, HEAD-INTERLEAVED output:
//    Y[row] holds float2 pairs P[c] = (col c, col c+HC).
// ---------------------------------------------------------------------------
template <int FI, int FO>
__global__ __launch_bounds__(256) void k_lin2t(
    const float* __restrict__ X,
    const float* __restrict__ Wl, const float* __restrict__ bl,
    const float* __restrict__ Wr, const float* __restrict__ br,
    float* __restrict__ Yl, float* __restrict__ Yr, int rows)
{
    constexpr int HC = FO / 2;
    constexpr int RG = 256 / HC;
    constexpr int R  = 8;
    constexpr int BR = RG * R;
    constexpr int F4 = FI / 4;
    __shared__ float xs[BR][FI];

    const int tid  = threadIdx.x;
    const int c    = tid % HC;
    const int g    = tid / HC;
    const int row0 = blockIdx.x * BR;

#pragma unroll
    for (int idx = tid; idx < BR * F4; idx += 256) {
        int r = idx / F4, q = idx % F4;
        reinterpret_cast<float4*>(&xs[r][0])[q] =
            reinterpret_cast<const float4*>(X + (size_t)(row0 + r) * FI)[q];
    }
    __syncthreads();

    float al0[R], al1[R], ar0[R], ar1[R];
    const float bl0 = bl[c], bl1 = bl[c + HC], br0 = br[c], br1 = br[c + HC];
#pragma unroll
    for (int r = 0; r < R; ++r) { al0[r] = bl0; al1[r] = bl1; ar0[r] = br0; ar1[r] = br1; }

    const int rb = g * R;
#pragma unroll
    for (int i0 = 0; i0 < FI; i0 += 4) {
        float4 xv[R];
#pragma unroll
        for (int r = 0; r < R; ++r)
            xv[r] = *reinterpret_cast<const float4*>(&xs[rb + r][i0]);
#pragma unroll
        for (int j = 0; j < 4; ++j) {
            const float wl0 = Wl[(i0 + j) * FO + c];
            const float wl1 = Wl[(i0 + j) * FO + c + HC];
            const float wr0 = Wr[(i0 + j) * FO + c];
            const float wr1 = Wr[(i0 + j) * FO + c + HC];
#pragma unroll
            for (int r = 0; r < R; ++r) {
                const float xx = (&xv[r].x)[j];
                al0[r] = fmaf(xx, wl0, al0[r]);
                al1[r] = fmaf(xx, wl1, al1[r]);
                ar0[r] = fmaf(xx, wr0, ar0[r]);
                ar1[r] = fmaf(xx, wr1, ar1[r]);
            }
        }
    }
#pragma unroll
    for (int r = 0; r < R; ++r) {
        const size_t ro = (size_t)(row0 + rb + r) * FO;
        reinterpret_cast<float2*>(Yl + ro)[c] = make_float2(al0[r], al1[r]);
        reinterpret_cast<float2*>(Yr + ro)[c] = make_float2(ar0[r], ar1[r]);
    }
}

// ---------------------------------------------------------------------------
// 2b. Single linear to 96 cols (GRU input gates): Y = X@W^T + b.
// ---------------------------------------------------------------------------
__global__ __launch_bounds__(192) void k_lin96(
    const float* __restrict__ X, const float* __restrict__ W,
    const float* __restrict__ b, float* __restrict__ Y)
{
    __shared__ float wT[32 * 97];       // wT[i*97+c] = W[c*32+i]
    __shared__ float xs[16][32];

    const int tid = threadIdx.y * 96 + threadIdx.x;
    const int row0 = blockIdx.x * 16;

    for (int idx = tid; idx < 3072; idx += 192) {
        int c = idx >> 5, i = idx & 31;
        wT[i * 97 + c] = W[idx];
    }
    for (int idx = tid; idx < 128; idx += 192)
        reinterpret_cast<float4*>(xs)[idx] =
            reinterpret_cast<const float4*>(X + (size_t)row0 * 32)[idx];
    __syncthreads();

    const int c  = threadIdx.x;
    const int rb = threadIdx.y * 8;
    float acc[8];
    const float bc = b[c];
#pragma unroll
    for (int r = 0; r < 8; ++r) acc[r] = bc;

#pragma unroll
    for (int i = 0; i < 32; ++i) {
        const float w = wT[i * 97 + c];
#pragma unroll
        for (int r = 0; r < 8; ++r)
            acc[r] = fmaf(xs[rb + r][i], w, acc[r]);
    }
#pragma unroll
    for (int r = 0; r < 8; ++r)
        Y[(size_t)(row0 + rb + r) * 96 + c] = acc[r];
}

// ---------------------------------------------------------------------------
// 2c. Serial GRU layer, input gates precomputed. One wave per 2 nodes.
// ---------------------------------------------------------------------------
__global__ __launch_bounds__(64) void k_gru1(
    const float* __restrict__ gi, const float* __restrict__ Whh,
    const float* __restrict__ bhh, float* __restrict__ E)
{
    const int d    = threadIdx.x & 31;
    const int node = blockIdx.x * 2 + (threadIdx.x >> 5);

    float wr_[32], wz_[32], wn_[32];
#pragma unroll
    for (int q = 0; q < 8; ++q) {
        *reinterpret_cast<float4*>(&wr_[q * 4]) =
            reinterpret_cast<const float4*>(Whh + (size_t)d * 32)[q];
        *reinterpret_cast<float4*>(&wz_[q * 4]) =
            reinterpret_cast<const float4*>(Whh + (size_t)(32 + d) * 32)[q];
        *reinterpret_cast<float4*>(&wn_[q * 4]) =
            reinterpret_cast<const float4*>(Whh + (size_t)(64 + d) * 32)[q];
    }
    const float br_ = bhh[d], bz_ = bhh[32 + d], bn_ = bhh[64 + d];

    float h = 0.0f;
    for (int t = 0; t < Tt; ++t) {
        const size_t base = ((size_t)t * Nn + node) * 96 + d;
        const float gr = gi[base], gz = gi[base + 32], gn = gi[base + 64];
        float ar = br_, az = bz_, an = bn_;
#pragma unroll
        for (int i = 0; i < 32; ++i) {
            const float hv = __shfl(h, i, 32);
            ar = fmaf(wr_[i], hv, ar);
            az = fmaf(wz_[i], hv, az);
            an = fmaf(wn_[i], hv, an);
        }
        const float r = 1.0f / (1.0f + expf(-(gr + ar)));
        const float z = 1.0f / (1.0f + expf(-(gz + az)));
        const float nn2 = tanhf(gn + r * an);
        h = (1.0f - z) * nn2 + z * h;
        E[((size_t)t * Nn + node) * 32 + d] = h;
    }
}

// ---------------------------------------------------------------------------
// 3. GATv2 C=64: DPP fold tree (logit[k] at lane rev4(k)), readlane alpha
//    broadcast, interleaved float2 gl/gr, optional fused MLP head.
// ---------------------------------------------------------------------------
template <bool HEAD>
__global__ __launch_bounds__(256) void k_gat64(
    const float* __restrict__ gl, const float* __restrict__ gr,
    const int* __restrict__ srcs, const float* __restrict__ att,
    const float* __restrict__ bias, float* __restrict__ out, int rows,
    const float* __restrict__ W2, const float* __restrict__ b2,
    const float* __restrict__ W3, const float* __restrict__ b3)
{
    __shared__ float hb[4][64];
    const int lane = threadIdx.x & 63;
    const int w = threadIdx.x >> 6;
    const int gridB = rows >> 2;
    const int chunk = gridB >> 3;
    const int bid = blockIdx.x;
    const int lb = (bid & 7) * chunk + (bid >> 3);
    const int wave = lb * 4 + w;
    const int t = wave >> 10;
    const int n = wave & (Nn - 1);

    const float2 grl = reinterpret_cast<const float2*>(gr + (size_t)wave * 128)[lane];
    const float a0 = att[lane], a1 = att[64 + lane];

    const int4* sp = reinterpret_cast<const int4*>(srcs + ((size_t)t * Nn + n) * KN);
    const int4 sA = sp[0], sB = sp[1], sC = sp[2], sD = sp[3];
    int s[KN] = {sA.x, sA.y, sA.z, sA.w, sB.x, sB.y, sB.z, sB.w,
                 sC.x, sC.y, sC.z, sC.w, sD.x, sD.y, sD.z, sD.w};

    float2 g[KN];
    float p0[KN], p1[KN];
#pragma unroll
    for (int k = 0; k < KN; ++k) {
        g[k] = reinterpret_cast<const float2*>(gl + ((size_t)t * Nn + s[k]) * 128)[lane];
        float e0 = g[k].x + grl.x; e0 = e0 > 0.0f ? e0 : 0.2f * e0;
        float e1 = g[k].y + grl.y; e1 = e1 > 0.0f ? e1 : 0.2f * e1;
        p0[k] = e0 * a0; p1[k] = e1 * a1;
    }
    // channel partial-fold (bits 0..3 hold k), finish channel sum over bits 4,5
    float lo0 = fold16(p0, lane);
    lo0 += lane_xor<16>(lo0); lo0 += __shfl_xor(lo0, 32);
    float lo1 = fold16(p1, lane);
    lo1 += lane_xor<16>(lo1); lo1 += __shfl_xor(lo1, 32);

    // softmax over k (lane bits 0..3)
    const float m0 = rmax16(lo0), m1 = rmax16(lo1);
    const float e0 = expf(lo0 - m0), e1 = expf(lo1 - m1);
    const float A0 = e0 / rsum16(e0), A1 = e1 / rsum16(e1);

    float acc0 = 0.0f, acc1 = 0.0f;
#pragma unroll
    for (int k = 0; k < KN; ++k) {
        acc0 = fmaf(bcastlane(A0, rev4(k)), g[k].x, acc0);
        acc1 = fmaf(bcastlane(A1, rev4(k)), g[k].y, acc1);
    }
    float res = 0.5f * (acc0 + acc1) + bias[lane];
    res = res > 0.0f ? res : expm1f(res);

    if (!HEAD) {
        out[(size_t)wave * 64 + lane] = res;
    } else {
        hb[w][lane] = res;
        __builtin_amdgcn_s_waitcnt(0);
        float acc = b2[lane];
#pragma unroll
        for (int i4 = 0; i4 < 16; ++i4) {
            const float4 hv = reinterpret_cast<const float4*>(&hb[w][0])[i4];
            acc = fmaf(hv.x, W2[(i4 * 4 + 0) * 64 + lane], acc);
            acc = fmaf(hv.y, W2[(i4 * 4 + 1) * 64 + lane], acc);
            acc = fmaf(hv.z, W2[(i4 * 4 + 2) * 64 + lane], acc);
            acc = fmaf(hv.w, W2[(i4 * 4 + 3) * 64 + lane], acc);
        }
        const float th = tanhf(acc);
        __builtin_amdgcn_s_waitcnt(0);
        hb[w][lane] = th;
        __builtin_amdgcn_s_waitcnt(0);
        if (lane < 50) {
            float a = b3[lane];
#pragma unroll
            for (int j4 = 0; j4 < 16; ++j4) {
                const float4 hv = reinterpret_cast<const float4*>(&hb[w][0])[j4];
                a = fmaf(hv.x, W3[(j4 * 4 + 0) * 50 + lane], a);
                a = fmaf(hv.y, W3[(j4 * 4 + 1) * 50 + lane], a);
                a = fmaf(hv.z, W3[(j4 * 4 + 2) * 50 + lane], a);
                a = fmaf(hv.w, W3[(j4 * 4 + 3) * 50 + lane], a);
            }
            out[(size_t)wave * 50 + lane] = a;
        }
    }
}

// ---------------------------------------------------------------------------
// 3b. GATv2 C=32: two targets per wave (halves). Folds/softmax within each
//     half (bits 0..3 + butterfly bit 4); alphas cross-swapped once (1 DS)
//     then readlane-broadcast.
// ---------------------------------------------------------------------------
__global__ __launch_bounds__(256) void k_gat32(
    const float* __restrict__ gl, const float* __restrict__ gr,
    const int* __restrict__ srcs, const float* __restrict__ att,
    const float* __restrict__ bias, float* __restrict__ out, int waves)
{
    const int lane = threadIdx.x & 63;
    const int w = threadIdx.x >> 6;
    const int gridB = waves >> 2;
    const int chunk = gridB >> 3;
    const int bid = blockIdx.x;
    const int lb = (bid & 7) * chunk + (bid >> 3);
    const int wv = lb * 4 + w;
    const int tgt = 2 * wv + (lane >> 5);
    const int t = tgt >> 10;
    const int n = tgt & (Nn - 1);
    const int c = lane & 31;

    const float2 grl = reinterpret_cast<const float2*>(gr + (size_t)tgt * 64)[c];
    const float a0 = att[c], a1 = att[32 + c];

    const int4* sp = reinterpret_cast<const int4*>(srcs + ((size_t)t * Nn + n) * KN);
    const int4 sA = sp[0], sB = sp[1], sC = sp[2], sD = sp[3];
    int s[KN] = {sA.x, sA.y, sA.z, sA.w, sB.x, sB.y, sB.z, sB.w,
                 sC.x, sC.y, sC.z, sC.w, sD.x, sD.y, sD.z, sD.w};

    float2 g[KN];
    float p0[KN], p1[KN];
#pragma unroll
    for (int k = 0; k < KN; ++k) {
        g[k] = reinterpret_cast<const float2*>(gl + ((size_t)t * Nn + s[k]) * 64)[c];
        float e0 = g[k].x + grl.x; e0 = e0 > 0.0f ? e0 : 0.2f * e0;
        float e1 = g[k].y + grl.y; e1 = e1 > 0.0f ? e1 : 0.2f * e1;
        p0[k] = e0 * a0; p1[k] = e1 * a1;
    }
    // channel fold within half: bits 0..3 hold k; finish channel sum over bit 4
    float lo0 = fold16(p0, lane); lo0 += lane_xor<16>(lo0);
    float lo1 = fold16(p1, lane); lo1 += lane_xor<16>(lo1);

    const float m0 = rmax16(lo0), m1 = rmax16(lo1);
    const float e0 = expf(lo0 - m0), e1 = expf(lo1 - m1);
    const float A0 = e0 / rsum16(e0), A1 = e1 / rsum16(e1);

    // cross-half alpha swap (one exchange instead of 32 bpermutes)
    const float A0o = __shfl_xor(A0, 32);
    const float A1o = __shfl_xor(A1, 32);
    const bool loHalf = (lane < 32);

    float acc0 = 0.0f, acc1 = 0.0f;
#pragma unroll
    for (int k = 0; k < KN; ++k) {
        const float b0a = bcastlane(A0, rev4(k)), b0b = bcastlane(A0o, rev4(k));
        const float b1a = bcastlane(A1, rev4(k)), b1b = bcastlane(A1o, rev4(k));
        acc0 = fmaf(loHalf ? b0a : b0b, g[k].x, acc0);
        acc1 = fmaf(loHalf ? b1a : b1b, g[k].y, acc1);
    }
    float res = 0.5f * (acc0 + acc1) + bias[c];
    res = res > 0.0f ? res : expm1f(res);
    out[(size_t)tgt * 32 + c] = res;
}

// ---------------------------------------------------------------------------
extern "C" void kernel_launch(void* const* d_in, const int* in_sizes, int n_in,
                              void* d_out, int out_size, void* d_ws, size_t ws_size,
                              hipStream_t stream)
{
    const float* x    = (const float*)d_in[0];
    const int*   edge = (const int*)d_in[1];

    const float *g1_Wl = (const float*)d_in[2],  *g1_bl = (const float*)d_in[3];
    const float *g1_Wr = (const float*)d_in[4],  *g1_br = (const float*)d_in[5];
    const float *g1_att= (const float*)d_in[6],  *g1_b  = (const float*)d_in[7];
    const float *g2_Wl = (const float*)d_in[8],  *g2_bl = (const float*)d_in[9];
    const float *g2_Wr = (const float*)d_in[10], *g2_br = (const float*)d_in[11];
    const float *g2_att= (const float*)d_in[12], *g2_b  = (const float*)d_in[13];
    const float *r1_Wl = (const float*)d_in[14], *r1_bl = (const float*)d_in[15];
    const float *r1_Wr = (const float*)d_in[16], *r1_br = (const float*)d_in[17];
    const float *r1_att= (const float*)d_in[18], *r1_b  = (const float*)d_in[19];
    const float *f1_Wl = (const float*)d_in[20], *f1_bl = (const float*)d_in[21];
    const float *f1_Wr = (const float*)d_in[22], *f1_br = (const float*)d_in[23];
    const float *f1_att= (const float*)d_in[24], *f1_b  = (const float*)d_in[25];
    const float *gru0_Wih = (const float*)d_in[26], *gru0_Whh = (const float*)d_in[27];
    const float *gru0_bih = (const float*)d_in[28], *gru0_bhh = (const float*)d_in[29];
    const float *gru1_Wih = (const float*)d_in[30], *gru1_Whh = (const float*)d_in[31];
    const float *gru1_bih = (const float*)d_in[32], *gru1_bhh = (const float*)d_in[33];
    const float *rec2_W = (const float*)d_in[34], *rec2_b = (const float*)d_in[35];
    const float *rec3_W = (const float*)d_in[36], *rec3_b = (const float*)d_in[37];
    const float *fore3_W= (const float*)d_in[38], *fore3_b= (const float*)d_in[39];

    // workspace layout
    char* ws = (char*)d_ws;
    int*   srcs = (int*)ws;                              // [32][1024][16] ints (2 MB)
    float* buf1 = (float*)(ws + (4u << 20));             // [32768,128] 16 MB
    float* buf2 = buf1 + (size_t)32768 * 128;            // [32768,128] 16 MB
    float* buf3 = buf2 + (size_t)32768 * 128;            // [32768,64]   8 MB
    float* buf4 = buf3 + (size_t)32768 * 64;             // [32768,32]   4 MB

    float* recon = (float*)d_out;                        // [31,1024,50]
    float* fore  = recon + (size_t)31 * 1024 * 50;       // [31,1024,50]
    float* E     = fore  + (size_t)31 * 1024 * 50;       // [32,1024,32]

    // 1. adjacency -> source lists (256 blocks, 8-deep int4 pipeline)
    k_srcs<<<Tt * 8, 1024, 0, stream>>>(edge, srcs);

    // 2. GAT g1 (64 -> 64)
    k_lin2t<64, 128><<<1024, 256, 0, stream>>>(x, g1_Wl, g1_bl, g1_Wr, g1_br, buf1, buf2, 32768);
    k_gat64<false><<<8192, 256, 0, stream>>>(buf1, buf2, srcs, g1_att, g1_b, buf3, 32768,
                                             nullptr, nullptr, nullptr, nullptr);

    // 3. GAT g2 (64 -> 32): 2 targets/wave
    k_lin2t<64, 64><<<512, 256, 0, stream>>>(buf3, g2_Wl, g2_bl, g2_Wr, g2_br, buf1, buf2, 32768);
    k_gat32<<<4096, 256, 0, stream>>>(buf1, buf2, srcs, g2_att, g2_b, buf4, 16384);

    // 4. two stacked GRUs -> E
    k_lin96<<<2048, dim3(96, 2), 0, stream>>>(buf4, gru0_Wih, gru0_bih, buf1);   // GI0
    k_gru1<<<512, 64, 0, stream>>>(buf1, gru0_Whh, gru0_bhh, buf3);              // E0
    k_lin96<<<2048, dim3(96, 2), 0, stream>>>(buf3, gru1_Wih, gru1_bih, buf2);   // GI1
    k_gru1<<<512, 64, 0, stream>>>(buf2, gru1_Whh, gru1_bhh, E);                 // E

    // 5. reconstruct: GAT r1 on E[1:] + fused tanh(@rec2)@rec3 head
    k_lin2t<32, 128><<<992, 256, 0, stream>>>(E + (size_t)Nn * 32, r1_Wl, r1_bl, r1_Wr, r1_br, buf1, buf2, 31744);
    k_gat64<true><<<7936, 256, 0, stream>>>(buf1, buf2, srcs + (size_t)KN * Nn, r1_att, r1_b, recon, 31744,
                                            rec2_W, rec2_b, rec3_W, rec3_b);

    // 6. forecast: GAT f1 on E[:-1] + fused tanh(@rec2)@fore3 head
    k_lin2t<32, 128><<<992, 256, 0, stream>>>(E, f1_Wl, f1_bl, f1_Wr, f1_br, buf1, buf2, 31744);
    k_gat64<true><<<7936, 256, 0, stream>>>(buf1, buf2, srcs, f1_att, f1_b, fore, 31744,
                                            rec2_W, rec2_b, fore3_W, fore3_b);

    (void)in_sizes; (void)n_in; (void)out_size; (void)ws_size;
}